// Round 1
// baseline (3159.328 us; speedup 1.0000x reference)
//
#include <hip/hip_runtime.h>

// GraphSAGE 2-layer + edge scorer, MI355X fp32 implementation.
// Rewrite: mean(h1[src]) @ W2n == mean((h1 @ W2n)[src])  -> both scatter
// phases are 128-dim. h2 never materialized: p = h2@Wp[:128], q = h2@Wp[128:],
// score[e] = p[src] + q[dst] + bp.

#define NN 50000
#define EM 800000
#define EPOS 200000
#define ENEG 200000

// workspace layout (float offsets)
#define O_CNT  0           // 50176 floats
#define O_AGG1 50176       // 6,400,000 (also reused as z2 after layer1)
#define O_AGGZ 6450176     // 6,400,000
#define O_H1   12850176    // 12,800,000
#define O_P    25650176    // 50176
#define O_Q    25700352    // 50176
// total 25,750,528 floats = 103 MB

__global__ __launch_bounds__(256) void count_kernel(const int* __restrict__ dst,
                                                    float* __restrict__ cnt, int n) {
    int i = blockIdx.x * blockDim.x + threadIdx.x;
    if (i < n) atomicAdd(&cnt[dst[i]], 1.0f);
}

// scatter-add 128-dim rows: feat[src[e]] += into agg[dst[e]]
__global__ __launch_bounds__(256) void scatter_kernel(const float* __restrict__ feat,
                                                      const int* __restrict__ src,
                                                      const int* __restrict__ dst,
                                                      float* __restrict__ agg, int nedges) {
    int tid = blockIdx.x * blockDim.x + threadIdx.x;
    int e = tid >> 5;           // 32 float4-chunks per 128-dim row
    if (e >= nedges) return;
    int c = (tid & 31) << 2;
    int s = src[e], d = dst[e];
    const float4 v = *(const float4*)(feat + s * 128 + c);
    float* a = agg + d * 128 + c;
    atomicAdd(a + 0, v.x);
    atomicAdd(a + 1, v.y);
    atomicAdd(a + 2, v.z);
    atomicAdd(a + 3, v.w);
}

// h1 = relu(x @ W1s + (agg1/cnt) @ W1n + b1), 8 nodes per block, 256 cols/thread-col
__global__ __launch_bounds__(256) void layer1_kernel(
    const float* __restrict__ x, const float* __restrict__ agg,
    const float* __restrict__ cnt, const float* __restrict__ W1s,
    const float* __restrict__ W1n, const float* __restrict__ b1,
    float* __restrict__ h1) {
    __shared__ float xs[8][128];
    __shared__ float as[8][128];
    int n0 = blockIdx.x * 8;
    int t = threadIdx.x;
    for (int i = t; i < 8 * 128; i += 256) {
        int r = i >> 7, k = i & 127;
        int n = n0 + r;
        xs[r][k] = x[n * 128 + k];
        float c = cnt[n]; if (c < 1.f) c = 1.f;
        as[r][k] = agg[n * 128 + k] / c;
    }
    __syncthreads();
    float acc[8];
    float bb = b1[t];
#pragma unroll
    for (int r = 0; r < 8; ++r) acc[r] = bb;
#pragma unroll 4
    for (int k = 0; k < 128; ++k) {
        float w_s = W1s[k * 256 + t];
        float w_n = W1n[k * 256 + t];
#pragma unroll
        for (int r = 0; r < 8; ++r)
            acc[r] += xs[r][k] * w_s + as[r][k] * w_n;
    }
#pragma unroll
    for (int r = 0; r < 8; ++r) {
        float v = acc[r] > 0.f ? acc[r] : 0.f;
        h1[(n0 + r) * 256 + t] = v;
    }
}

// z2 = h1 @ W2n  (K=256 -> 128 cols), 8 nodes/block
__global__ __launch_bounds__(256) void z2_kernel(
    const float* __restrict__ h1, const float* __restrict__ W2n,
    float* __restrict__ z2) {
    __shared__ float hs[8][256];
    int n0 = blockIdx.x * 8;
    int t = threadIdx.x;
    for (int i = t; i < 8 * 256; i += 256) {
        int r = i >> 8, k = i & 255;
        hs[r][k] = h1[(n0 + r) * 256 + k];
    }
    __syncthreads();
    int c = t & 127, g = t >> 7;   // g selects row group {g*4 .. g*4+3}
    float acc[4] = {0.f, 0.f, 0.f, 0.f};
#pragma unroll 4
    for (int k = 0; k < 256; ++k) {
        float w = W2n[k * 128 + c];
#pragma unroll
        for (int j = 0; j < 4; ++j) acc[j] += hs[g * 4 + j][k] * w;
    }
#pragma unroll
    for (int j = 0; j < 4; ++j) z2[(n0 + g * 4 + j) * 128 + c] = acc[j];
}

// h2 = h1 @ W2s + aggz/cnt + b2 ; p = h2.wp[:128], q = h2.wp[128:]
__global__ __launch_bounds__(256) void final_kernel(
    const float* __restrict__ h1, const float* __restrict__ aggz,
    const float* __restrict__ cnt, const float* __restrict__ W2s,
    const float* __restrict__ b2, const float* __restrict__ wp,
    float* __restrict__ p, float* __restrict__ q) {
    __shared__ float hs[8][256];
    __shared__ float redp[8][128];
    __shared__ float redq[8][128];
    int n0 = blockIdx.x * 8;
    int t = threadIdx.x;
    for (int i = t; i < 8 * 256; i += 256) {
        int r = i >> 8, k = i & 255;
        hs[r][k] = h1[(n0 + r) * 256 + k];
    }
    __syncthreads();
    int c = t & 127, g = t >> 7;
    float acc[4];
#pragma unroll
    for (int j = 0; j < 4; ++j) {
        int n = n0 + g * 4 + j;
        float cc = cnt[n]; if (cc < 1.f) cc = 1.f;
        acc[j] = b2[c] + aggz[n * 128 + c] / cc;
    }
#pragma unroll 4
    for (int k = 0; k < 256; ++k) {
        float w = W2s[k * 128 + c];
#pragma unroll
        for (int j = 0; j < 4; ++j) acc[j] += hs[g * 4 + j][k] * w;
    }
    float wpc = wp[c], wqc = wp[128 + c];
#pragma unroll
    for (int j = 0; j < 4; ++j) {
        redp[g * 4 + j][c] = acc[j] * wpc;
        redq[g * 4 + j][c] = acc[j] * wqc;
    }
    __syncthreads();
    for (int s = 64; s >= 1; s >>= 1) {
        if (c < s) {
#pragma unroll
            for (int j = 0; j < 4; ++j) {
                redp[g * 4 + j][c] += redp[g * 4 + j][c + s];
                redq[g * 4 + j][c] += redq[g * 4 + j][c + s];
            }
        }
        __syncthreads();
    }
    if (c == 0) {
#pragma unroll
        for (int j = 0; j < 4; ++j) {
            p[n0 + g * 4 + j] = redp[g * 4 + j][0];
            q[n0 + g * 4 + j] = redq[g * 4 + j][0];
        }
    }
}

__global__ __launch_bounds__(256) void score_kernel(
    const int* __restrict__ psrc, const int* __restrict__ pdst,
    const int* __restrict__ nsrc, const int* __restrict__ ndst,
    const float* __restrict__ p, const float* __restrict__ q,
    const float* __restrict__ bp, float* __restrict__ out) {
    int i = blockIdx.x * blockDim.x + threadIdx.x;
    float b = bp[0];
    if (i < EPOS) {
        out[i] = p[psrc[i]] + q[pdst[i]] + b;
    } else if (i < EPOS + ENEG) {
        int j = i - EPOS;
        out[i] = p[nsrc[j]] + q[ndst[j]] + b;
    }
}

extern "C" void kernel_launch(void* const* d_in, const int* in_sizes, int n_in,
                              void* d_out, int out_size, void* d_ws, size_t ws_size,
                              hipStream_t stream) {
    const float* x    = (const float*)d_in[0];
    const int*   msrc = (const int*)d_in[1];
    const int*   mdst = (const int*)d_in[2];
    const int*   psrc = (const int*)d_in[3];
    const int*   pdst = (const int*)d_in[4];
    const int*   nsrc = (const int*)d_in[5];
    const int*   ndst = (const int*)d_in[6];
    const float* W1s  = (const float*)d_in[7];
    const float* W1n  = (const float*)d_in[8];
    const float* b1   = (const float*)d_in[9];
    const float* W2s  = (const float*)d_in[10];
    const float* W2n  = (const float*)d_in[11];
    const float* b2   = (const float*)d_in[12];
    const float* wp   = (const float*)d_in[13];
    const float* bp   = (const float*)d_in[14];

    float* ws   = (float*)d_ws;
    float* cnt  = ws + O_CNT;
    float* agg1 = ws + O_AGG1;
    float* z2   = agg1;            // alias: agg1 dead after layer1_kernel
    float* aggz = ws + O_AGGZ;
    float* h1   = ws + O_H1;
    float* p    = ws + O_P;
    float* q    = ws + O_Q;
    float* out  = (float*)d_out;

    // zero cnt + agg1 + aggz in one contiguous memset
    hipMemsetAsync(d_ws, 0, (size_t)O_H1 * sizeof(float), stream);

    count_kernel<<<(EM + 255) / 256, 256, 0, stream>>>(mdst, cnt, EM);
    scatter_kernel<<<(EM * 32 + 255) / 256, 256, 0, stream>>>(x, msrc, mdst, agg1, EM);
    layer1_kernel<<<NN / 8, 256, 0, stream>>>(x, agg1, cnt, W1s, W1n, b1, h1);
    z2_kernel<<<NN / 8, 256, 0, stream>>>(h1, W2n, z2);
    scatter_kernel<<<(EM * 32 + 255) / 256, 256, 0, stream>>>(z2, msrc, mdst, aggz, EM);
    final_kernel<<<NN / 8, 256, 0, stream>>>(h1, aggz, cnt, W2s, b2, wp, p, q);
    score_kernel<<<(EPOS + ENEG + 255) / 256, 256, 0, stream>>>(
        psrc, pdst, nsrc, ndst, p, q, bp, out);
}

// Round 2
// 733.121 us; speedup vs baseline: 4.3094x; 4.3094x over previous
//
#include <hip/hip_runtime.h>

// GraphSAGE 2-layer + edge scorer, MI355X fp32.
// R2: atomic scatter -> CSR gather. Build CSR(dst) once per call (histogram +
// scan + bucket), then gather-mean per node with one wave/node. Both
// aggregations reuse the same CSR. Algebraic rewrite kept:
// mean(h1[src]) @ W2n == mean((h1@W2n)[src]) -> both gathers are 128-dim.
// h2 never materialized: p = h2@Wp[:128], q = h2@Wp[128:], score = p[s]+q[d]+bp.

#define NN 50000
#define EM 800000
#define EPOS 200000
#define ENEG 200000

// workspace layout (4-byte word offsets)
#define I_CNT 0            // 50176 ints (histogram; free after scan)
#define I_ROW 50176        // 50432 ints (rowstart, NN+1 used)
#define I_CUR 100608       // 50176 ints (bucket cursors)
#define I_CSR 150784       // 800000 ints (edge srcs sorted by dst)
#define F0    950784       // float region start
#define O_AGG1 (F0)              // 6,400,000 (aliased as z2 after layer1)
#define O_AGGZ (F0 + 6400000)    // 6,400,000
#define O_H1   (F0 + 12800000)   // 12,800,000
#define O_P    (F0 + 25600000)   // 50176
#define O_Q    (F0 + 25650176)   // 50176
// total 26,651,136 words = 106.6 MB

__global__ __launch_bounds__(256) void count_kernel(const int* __restrict__ dst,
                                                    int* __restrict__ cnt, int n) {
    int i = blockIdx.x * blockDim.x + threadIdx.x;
    if (i < n) atomicAdd(&cnt[dst[i]], 1);
}

// exclusive scan of cnt[0..NN) -> rowstart (and a second copy in cursor).
// Single block, 1024 threads, 49 elems/thread.
__global__ __launch_bounds__(1024) void scan_kernel(const int* __restrict__ cnt,
                                                    int* __restrict__ rowstart,
                                                    int* __restrict__ cursor) {
    __shared__ int part[1024];
    const int CH = (NN + 1023) / 1024;  // 49
    int t = threadIdx.x;
    int base = t * CH;
    int s = 0;
    for (int i = 0; i < CH; ++i) {
        int idx = base + i;
        if (idx < NN) s += cnt[idx];
    }
    part[t] = s;
    __syncthreads();
    for (int off = 1; off < 1024; off <<= 1) {
        int v = (t >= off) ? part[t - off] : 0;
        __syncthreads();
        part[t] += v;
        __syncthreads();
    }
    int run = (t == 0) ? 0 : part[t - 1];
    for (int i = 0; i < CH; ++i) {
        int idx = base + i;
        if (idx < NN) {
            rowstart[idx] = run;
            cursor[idx] = run;
            run += cnt[idx];
        }
    }
    if (t == 0) rowstart[NN] = EM;
}

__global__ __launch_bounds__(256) void bucket_kernel(const int* __restrict__ src,
                                                     const int* __restrict__ dst,
                                                     int* __restrict__ cursor,
                                                     int* __restrict__ csr_src, int n) {
    int e = blockIdx.x * blockDim.x + threadIdx.x;
    if (e < n) {
        int d = dst[e];
        int pos = atomicAdd(&cursor[d], 1);
        csr_src[pos] = src[e];
    }
}

// one wave per node: mean of feat[src] rows (128 floats) over its CSR bucket
__global__ __launch_bounds__(256) void gather_kernel(const float* __restrict__ feat,
                                                     const int* __restrict__ rowstart,
                                                     const int* __restrict__ csr_src,
                                                     float* __restrict__ agg) {
    int node = (blockIdx.x * 256 + threadIdx.x) >> 6;
    if (node >= NN) return;
    int lane = threadIdx.x & 63;
    int c = lane * 2;
    int beg = rowstart[node], end = rowstart[node + 1];
    float ax = 0.f, ay = 0.f;
    int i = beg;
    for (; i + 3 < end; i += 4) {
        int s0 = csr_src[i], s1 = csr_src[i + 1];
        int s2 = csr_src[i + 2], s3 = csr_src[i + 3];
        float2 v0 = *(const float2*)(feat + (size_t)s0 * 128 + c);
        float2 v1 = *(const float2*)(feat + (size_t)s1 * 128 + c);
        float2 v2 = *(const float2*)(feat + (size_t)s2 * 128 + c);
        float2 v3 = *(const float2*)(feat + (size_t)s3 * 128 + c);
        ax += v0.x + v1.x + v2.x + v3.x;
        ay += v0.y + v1.y + v2.y + v3.y;
    }
    for (; i < end; ++i) {
        int s = csr_src[i];
        float2 v = *(const float2*)(feat + (size_t)s * 128 + c);
        ax += v.x;
        ay += v.y;
    }
    int deg = end - beg;
    float inv = 1.0f / (float)(deg > 0 ? deg : 1);
    agg[(size_t)node * 128 + c] = ax * inv;
    agg[(size_t)node * 128 + c + 1] = ay * inv;
}

// h1 = relu(x @ W1s + agg1 @ W1n + b1), agg1 already the mean
__global__ __launch_bounds__(256) void layer1_kernel(
    const float* __restrict__ x, const float* __restrict__ agg,
    const float* __restrict__ W1s, const float* __restrict__ W1n,
    const float* __restrict__ b1, float* __restrict__ h1) {
    __shared__ float xs[8][128];
    __shared__ float as[8][128];
    int n0 = blockIdx.x * 8;
    int t = threadIdx.x;
    for (int i = t; i < 8 * 128; i += 256) {
        int r = i >> 7, k = i & 127;
        int n = n0 + r;
        xs[r][k] = x[n * 128 + k];
        as[r][k] = agg[n * 128 + k];
    }
    __syncthreads();
    float acc[8];
    float bb = b1[t];
#pragma unroll
    for (int r = 0; r < 8; ++r) acc[r] = bb;
#pragma unroll 4
    for (int k = 0; k < 128; ++k) {
        float w_s = W1s[k * 256 + t];
        float w_n = W1n[k * 256 + t];
#pragma unroll
        for (int r = 0; r < 8; ++r)
            acc[r] += xs[r][k] * w_s + as[r][k] * w_n;
    }
#pragma unroll
    for (int r = 0; r < 8; ++r) {
        float v = acc[r] > 0.f ? acc[r] : 0.f;
        h1[(n0 + r) * 256 + t] = v;
    }
}

// z2 = h1 @ W2n  (K=256 -> 128 cols), 8 nodes/block
__global__ __launch_bounds__(256) void z2_kernel(
    const float* __restrict__ h1, const float* __restrict__ W2n,
    float* __restrict__ z2) {
    __shared__ float hs[8][256];
    int n0 = blockIdx.x * 8;
    int t = threadIdx.x;
    for (int i = t; i < 8 * 256; i += 256) {
        int r = i >> 8, k = i & 255;
        hs[r][k] = h1[(n0 + r) * 256 + k];
    }
    __syncthreads();
    int c = t & 127, g = t >> 7;
    float acc[4] = {0.f, 0.f, 0.f, 0.f};
#pragma unroll 4
    for (int k = 0; k < 256; ++k) {
        float w = W2n[k * 128 + c];
#pragma unroll
        for (int j = 0; j < 4; ++j) acc[j] += hs[g * 4 + j][k] * w;
    }
#pragma unroll
    for (int j = 0; j < 4; ++j) z2[(n0 + g * 4 + j) * 128 + c] = acc[j];
}

// h2 = h1 @ W2s + aggz + b2 (aggz already mean); p = h2.wp[:128], q = h2.wp[128:]
__global__ __launch_bounds__(256) void final_kernel(
    const float* __restrict__ h1, const float* __restrict__ aggz,
    const float* __restrict__ W2s, const float* __restrict__ b2,
    const float* __restrict__ wp, float* __restrict__ p, float* __restrict__ q) {
    __shared__ float hs[8][256];
    __shared__ float redp[8][128];
    __shared__ float redq[8][128];
    int n0 = blockIdx.x * 8;
    int t = threadIdx.x;
    for (int i = t; i < 8 * 256; i += 256) {
        int r = i >> 8, k = i & 255;
        hs[r][k] = h1[(n0 + r) * 256 + k];
    }
    __syncthreads();
    int c = t & 127, g = t >> 7;
    float acc[4];
#pragma unroll
    for (int j = 0; j < 4; ++j) {
        int n = n0 + g * 4 + j;
        acc[j] = b2[c] + aggz[n * 128 + c];
    }
#pragma unroll 4
    for (int k = 0; k < 256; ++k) {
        float w = W2s[k * 128 + c];
#pragma unroll
        for (int j = 0; j < 4; ++j) acc[j] += hs[g * 4 + j][k] * w;
    }
    float wpc = wp[c], wqc = wp[128 + c];
#pragma unroll
    for (int j = 0; j < 4; ++j) {
        redp[g * 4 + j][c] = acc[j] * wpc;
        redq[g * 4 + j][c] = acc[j] * wqc;
    }
    __syncthreads();
    for (int s = 64; s >= 1; s >>= 1) {
        if (c < s) {
#pragma unroll
            for (int j = 0; j < 4; ++j) {
                redp[g * 4 + j][c] += redp[g * 4 + j][c + s];
                redq[g * 4 + j][c] += redq[g * 4 + j][c + s];
            }
        }
        __syncthreads();
    }
    if (c == 0) {
#pragma unroll
        for (int j = 0; j < 4; ++j) {
            p[n0 + g * 4 + j] = redp[g * 4 + j][0];
            q[n0 + g * 4 + j] = redq[g * 4 + j][0];
        }
    }
}

__global__ __launch_bounds__(256) void score_kernel(
    const int* __restrict__ psrc, const int* __restrict__ pdst,
    const int* __restrict__ nsrc, const int* __restrict__ ndst,
    const float* __restrict__ p, const float* __restrict__ q,
    const float* __restrict__ bp, float* __restrict__ out) {
    int i = blockIdx.x * blockDim.x + threadIdx.x;
    float b = bp[0];
    if (i < EPOS) {
        out[i] = p[psrc[i]] + q[pdst[i]] + b;
    } else if (i < EPOS + ENEG) {
        int j = i - EPOS;
        out[i] = p[nsrc[j]] + q[ndst[j]] + b;
    }
}

extern "C" void kernel_launch(void* const* d_in, const int* in_sizes, int n_in,
                              void* d_out, int out_size, void* d_ws, size_t ws_size,
                              hipStream_t stream) {
    const float* x    = (const float*)d_in[0];
    const int*   msrc = (const int*)d_in[1];
    const int*   mdst = (const int*)d_in[2];
    const int*   psrc = (const int*)d_in[3];
    const int*   pdst = (const int*)d_in[4];
    const int*   nsrc = (const int*)d_in[5];
    const int*   ndst = (const int*)d_in[6];
    const float* W1s  = (const float*)d_in[7];
    const float* W1n  = (const float*)d_in[8];
    const float* b1   = (const float*)d_in[9];
    const float* W2s  = (const float*)d_in[10];
    const float* W2n  = (const float*)d_in[11];
    const float* b2   = (const float*)d_in[12];
    const float* wp   = (const float*)d_in[13];
    const float* bp   = (const float*)d_in[14];

    int*   iw   = (int*)d_ws;
    float* fw   = (float*)d_ws;
    int*   cnt     = iw + I_CNT;
    int*   rowstart= iw + I_ROW;
    int*   cursor  = iw + I_CUR;
    int*   csr_src = iw + I_CSR;
    float* agg1 = fw + O_AGG1;
    float* z2   = agg1;            // alias: agg1 dead after layer1_kernel
    float* aggz = fw + O_AGGZ;
    float* h1   = fw + O_H1;
    float* p    = fw + O_P;
    float* q    = fw + O_Q;
    float* out  = (float*)d_out;

    // zero only the histogram (200 KB)
    hipMemsetAsync(cnt, 0, 50176 * sizeof(int), stream);

    count_kernel<<<(EM + 255) / 256, 256, 0, stream>>>(mdst, cnt, EM);
    scan_kernel<<<1, 1024, 0, stream>>>(cnt, rowstart, cursor);
    bucket_kernel<<<(EM + 255) / 256, 256, 0, stream>>>(msrc, mdst, cursor, csr_src, EM);

    gather_kernel<<<(NN * 64 + 255) / 256, 256, 0, stream>>>(x, rowstart, csr_src, agg1);
    layer1_kernel<<<NN / 8, 256, 0, stream>>>(x, agg1, W1s, W1n, b1, h1);
    z2_kernel<<<NN / 8, 256, 0, stream>>>(h1, W2n, z2);
    gather_kernel<<<(NN * 64 + 255) / 256, 256, 0, stream>>>(z2, rowstart, csr_src, aggz);
    final_kernel<<<NN / 8, 256, 0, stream>>>(h1, aggz, W2s, b2, wp, p, q);
    score_kernel<<<(EPOS + ENEG + 255) / 256, 256, 0, stream>>>(
        psrc, pdst, nsrc, ndst, p, q, bp, out);
}

// Round 3
// 537.783 us; speedup vs baseline: 5.8747x; 1.3632x over previous
//
#include <hip/hip_runtime.h>

// GraphSAGE 2-layer + edge scorer, MI355X.
// R3: GEMMs -> bf16 MFMA (16x16x32, fp32 accum). Tables gathered in bf16.
// Structure: CSR build -> convert x,W -> gather1 -> gemm1(relu) ->
// gemm2(z2 bf16 + h2self fp32) -> gather2+epilogue(p,q) -> score.
// Rewrites kept: mean(h1[src])@W2n == mean((h1@W2n)[src]); h2 never
// materialized: score = p[src] + q[dst] + bp.

#define NN 50000
#define EM 800000
#define EPOS 200000
#define ENEG 200000

typedef __bf16 bf16;
typedef bf16 bf16x2 __attribute__((ext_vector_type(2)));
typedef bf16 bf16x4 __attribute__((ext_vector_type(4)));
typedef bf16 bf16x8 __attribute__((ext_vector_type(8)));
typedef float floatx4 __attribute__((ext_vector_type(4)));

// ---- workspace byte offsets (all 16B-aligned) ----
#define I_CNT 0              // 50176 ints
#define I_ROW 50176          // ints
#define I_CUR 100608         // ints
#define I_CSR 150784         // 800000 ints, ints end at word 950784
#define B_XB   3803136       // 6.4M bf16 (12.8 MB)
#define B_AGG1 16603136      // 6.4M bf16
#define B_H1   29403136      // 12.8M bf16 (25.6 MB)
#define B_Z2   55003136      // 6.4M bf16
#define B_H2S  67803136      // 6.4M fp32 (25.6 MB)
#define B_WT1  93403136      // 65536 bf16
#define B_WT2  93534208      // 65536 bf16
#define B_P    93665280      // 50176 fp32
#define B_Q    93865984      // 50176 fp32
// end ~94.1 MB

__global__ __launch_bounds__(256) void count_kernel(const int* __restrict__ dst,
                                                    int* __restrict__ cnt, int n) {
    int i = blockIdx.x * blockDim.x + threadIdx.x;
    if (i < n) atomicAdd(&cnt[dst[i]], 1);
}

__global__ __launch_bounds__(1024) void scan_kernel(const int* __restrict__ cnt,
                                                    int* __restrict__ rowstart,
                                                    int* __restrict__ cursor) {
    __shared__ int part[1024];
    const int CH = (NN + 1023) / 1024;
    int t = threadIdx.x;
    int base = t * CH;
    int s = 0;
    for (int i = 0; i < CH; ++i) {
        int idx = base + i;
        if (idx < NN) s += cnt[idx];
    }
    part[t] = s;
    __syncthreads();
    for (int off = 1; off < 1024; off <<= 1) {
        int v = (t >= off) ? part[t - off] : 0;
        __syncthreads();
        part[t] += v;
        __syncthreads();
    }
    int run = (t == 0) ? 0 : part[t - 1];
    for (int i = 0; i < CH; ++i) {
        int idx = base + i;
        if (idx < NN) {
            rowstart[idx] = run;
            cursor[idx] = run;
            run += cnt[idx];
        }
    }
    if (t == 0) rowstart[NN] = EM;
}

__global__ __launch_bounds__(256) void bucket_kernel(const int* __restrict__ src,
                                                     const int* __restrict__ dst,
                                                     int* __restrict__ cursor,
                                                     int* __restrict__ csr_src, int n) {
    int e = blockIdx.x * blockDim.x + threadIdx.x;
    if (e < n) {
        int d = dst[e];
        int pos = atomicAdd(&cursor[d], 1);
        csr_src[pos] = src[e];
    }
}

// x fp32 -> bf16, 4 elems/thread
__global__ __launch_bounds__(256) void convx_kernel(const float* __restrict__ x,
                                                    bf16* __restrict__ xb) {
    int i = blockIdx.x * 256 + threadIdx.x;
    if (i >= NN * 128 / 4) return;
    float4 v = ((const float4*)x)[i];
    bf16x4 o;
    o[0] = (bf16)v.x; o[1] = (bf16)v.y; o[2] = (bf16)v.z; o[3] = (bf16)v.w;
    *(bf16x4*)(xb + (size_t)i * 4) = o;
}

// Wt1[n][k] = k<128 ? W1s[k][n] : W1n[k-128][n]   (256x256, n-major)
// Wt2[n][k] = n<128 ? W2n[k][n] : W2s[k][n-128]
__global__ __launch_bounds__(256) void convw_kernel(
    const float* __restrict__ W1s, const float* __restrict__ W1n,
    const float* __restrict__ W2n, const float* __restrict__ W2s,
    bf16* __restrict__ Wt1, bf16* __restrict__ Wt2) {
    int i = blockIdx.x * 256 + threadIdx.x;
    if (i >= 65536) return;
    int n = i >> 8, k = i & 255;
    float w1 = (k < 128) ? W1s[k * 256 + n] : W1n[(k - 128) * 256 + n];
    Wt1[i] = (bf16)w1;
    float w2 = (n < 128) ? W2n[k * 128 + n] : W2s[k * 128 + (n - 128)];
    Wt2[i] = (bf16)w2;
}

// one wave per node: mean of bf16 feat rows over CSR bucket -> bf16 agg
__global__ __launch_bounds__(256) void gather1_kernel(const bf16* __restrict__ feat,
                                                      const int* __restrict__ rowstart,
                                                      const int* __restrict__ csr,
                                                      bf16* __restrict__ agg) {
    int node = (blockIdx.x * 256 + threadIdx.x) >> 6;
    if (node >= NN) return;
    int lane = threadIdx.x & 63;
    int c = lane * 2;
    int beg = rowstart[node], end = rowstart[node + 1];
    float ax = 0.f, ay = 0.f;
    int i = beg;
    for (; i + 3 < end; i += 4) {
        int s0 = csr[i], s1 = csr[i + 1], s2 = csr[i + 2], s3 = csr[i + 3];
        bf16x2 v0 = *(const bf16x2*)(feat + (size_t)s0 * 128 + c);
        bf16x2 v1 = *(const bf16x2*)(feat + (size_t)s1 * 128 + c);
        bf16x2 v2 = *(const bf16x2*)(feat + (size_t)s2 * 128 + c);
        bf16x2 v3 = *(const bf16x2*)(feat + (size_t)s3 * 128 + c);
        ax += (float)v0[0] + (float)v1[0] + (float)v2[0] + (float)v3[0];
        ay += (float)v0[1] + (float)v1[1] + (float)v2[1] + (float)v3[1];
    }
    for (; i < end; ++i) {
        int s = csr[i];
        bf16x2 v = *(const bf16x2*)(feat + (size_t)s * 128 + c);
        ax += (float)v[0];
        ay += (float)v[1];
    }
    int deg = end - beg;
    float inv = 1.0f / (float)(deg > 0 ? deg : 1);
    bf16x2 o;
    o[0] = (bf16)(ax * inv);
    o[1] = (bf16)(ay * inv);
    *(bf16x2*)(agg + (size_t)node * 128 + c) = o;
}

// h1 = relu([xb | agg1b] @ Wt1^T + b1) -> bf16.  M=50000, K=256, N=256.
// Block = 4 waves, each wave 16 rows x 256 cols (16 MFMA col-tiles).
__global__ __launch_bounds__(256) void gemm1_kernel(
    const bf16* __restrict__ xb, const bf16* __restrict__ aggb,
    const bf16* __restrict__ Wt, const float* __restrict__ b1,
    bf16* __restrict__ h1b) {
    int wave = threadIdx.x >> 6;
    int lane = threadIdx.x & 63;
    int m0 = blockIdx.x * 64 + wave * 16;
    int r = lane & 15, quad = lane >> 4;
    int row = m0 + r; if (row >= NN) row = NN - 1;
    floatx4 acc[16];
#pragma unroll
    for (int t = 0; t < 16; ++t) acc[t] = (floatx4){0.f, 0.f, 0.f, 0.f};
    for (int k0 = 0; k0 < 256; k0 += 32) {
        int k = k0 + quad * 8;
        const bf16* abase = (k < 128) ? (xb + (size_t)row * 128 + k)
                                      : (aggb + (size_t)row * 128 + (k - 128));
        bf16x8 a = *(const bf16x8*)abase;
#pragma unroll
        for (int t = 0; t < 16; ++t) {
            bf16x8 b = *(const bf16x8*)(Wt + (size_t)(t * 16 + r) * 256 + k);
            acc[t] = __builtin_amdgcn_mfma_f32_16x16x32_bf16(a, b, acc[t], 0, 0, 0);
        }
    }
    int mbase = m0 + quad * 4;
#pragma unroll
    for (int t = 0; t < 16; ++t) {
        int col = t * 16 + r;
        float bb = b1[col];
#pragma unroll
        for (int rr = 0; rr < 4; ++rr) {
            int gm = mbase + rr;
            if (gm < NN) {
                float v = acc[t][rr] + bb;
                v = v > 0.f ? v : 0.f;
                h1b[(size_t)gm * 256 + col] = (bf16)v;
            }
        }
    }
}

// [z2 | h2self] = h1b @ Wt2^T (+b2 on right half). z2 bf16, h2self fp32.
__global__ __launch_bounds__(256) void gemm2_kernel(
    const bf16* __restrict__ h1b, const bf16* __restrict__ Wt,
    const float* __restrict__ b2, bf16* __restrict__ z2b,
    float* __restrict__ h2s) {
    int wave = threadIdx.x >> 6;
    int lane = threadIdx.x & 63;
    int m0 = blockIdx.x * 64 + wave * 16;
    int r = lane & 15, quad = lane >> 4;
    int row = m0 + r; if (row >= NN) row = NN - 1;
    floatx4 acc[16];
#pragma unroll
    for (int t = 0; t < 16; ++t) acc[t] = (floatx4){0.f, 0.f, 0.f, 0.f};
    for (int k0 = 0; k0 < 256; k0 += 32) {
        int k = k0 + quad * 8;
        bf16x8 a = *(const bf16x8*)(h1b + (size_t)row * 256 + k);
#pragma unroll
        for (int t = 0; t < 16; ++t) {
            bf16x8 b = *(const bf16x8*)(Wt + (size_t)(t * 16 + r) * 256 + k);
            acc[t] = __builtin_amdgcn_mfma_f32_16x16x32_bf16(a, b, acc[t], 0, 0, 0);
        }
    }
    int mbase = m0 + quad * 4;
#pragma unroll
    for (int t = 0; t < 8; ++t) {   // left half -> z2 (bf16)
        int col = t * 16 + r;
#pragma unroll
        for (int rr = 0; rr < 4; ++rr) {
            int gm = mbase + rr;
            if (gm < NN) z2b[(size_t)gm * 128 + col] = (bf16)acc[t][rr];
        }
    }
#pragma unroll
    for (int t = 8; t < 16; ++t) {  // right half -> h2self + b2 (fp32)
        int col = t * 16 + r - 128;
        float bb = b2[col];
#pragma unroll
        for (int rr = 0; rr < 4; ++rr) {
            int gm = mbase + rr;
            if (gm < NN) h2s[(size_t)gm * 128 + col] = acc[t + 0][rr] + bb;
        }
    }
}

// gather2 + full epilogue: mean(z2[neighbors]) + h2self -> h2;
// p = h2 . wp[:128], q = h2 . wp[128:]. One wave per node.
__global__ __launch_bounds__(256) void gather2_kernel(
    const bf16* __restrict__ z2b, const int* __restrict__ rowstart,
    const int* __restrict__ csr, const float* __restrict__ h2s,
    const float* __restrict__ wp, float* __restrict__ p, float* __restrict__ q) {
    int node = (blockIdx.x * 256 + threadIdx.x) >> 6;
    if (node >= NN) return;
    int lane = threadIdx.x & 63;
    int c = lane * 2;
    int beg = rowstart[node], end = rowstart[node + 1];
    float ax = 0.f, ay = 0.f;
    int i = beg;
    for (; i + 3 < end; i += 4) {
        int s0 = csr[i], s1 = csr[i + 1], s2 = csr[i + 2], s3 = csr[i + 3];
        bf16x2 v0 = *(const bf16x2*)(z2b + (size_t)s0 * 128 + c);
        bf16x2 v1 = *(const bf16x2*)(z2b + (size_t)s1 * 128 + c);
        bf16x2 v2 = *(const bf16x2*)(z2b + (size_t)s2 * 128 + c);
        bf16x2 v3 = *(const bf16x2*)(z2b + (size_t)s3 * 128 + c);
        ax += (float)v0[0] + (float)v1[0] + (float)v2[0] + (float)v3[0];
        ay += (float)v0[1] + (float)v1[1] + (float)v2[1] + (float)v3[1];
    }
    for (; i < end; ++i) {
        int s = csr[i];
        bf16x2 v = *(const bf16x2*)(z2b + (size_t)s * 128 + c);
        ax += (float)v[0];
        ay += (float)v[1];
    }
    int deg = end - beg;
    float inv = 1.0f / (float)(deg > 0 ? deg : 1);
    float v0 = h2s[(size_t)node * 128 + c] + ax * inv;      // b2 already added
    float v1 = h2s[(size_t)node * 128 + c + 1] + ay * inv;
    float pa = v0 * wp[c] + v1 * wp[c + 1];
    float qa = v0 * wp[128 + c] + v1 * wp[129 + c];
#pragma unroll
    for (int off = 32; off > 0; off >>= 1) {
        pa += __shfl_down(pa, off);
        qa += __shfl_down(qa, off);
    }
    if (lane == 0) {
        p[node] = pa;
        q[node] = qa;
    }
}

__global__ __launch_bounds__(256) void score_kernel(
    const int* __restrict__ psrc, const int* __restrict__ pdst,
    const int* __restrict__ nsrc, const int* __restrict__ ndst,
    const float* __restrict__ p, const float* __restrict__ q,
    const float* __restrict__ bp, float* __restrict__ out) {
    int i = blockIdx.x * blockDim.x + threadIdx.x;
    float b = bp[0];
    if (i < EPOS) {
        out[i] = p[psrc[i]] + q[pdst[i]] + b;
    } else if (i < EPOS + ENEG) {
        int j = i - EPOS;
        out[i] = p[nsrc[j]] + q[ndst[j]] + b;
    }
}

extern "C" void kernel_launch(void* const* d_in, const int* in_sizes, int n_in,
                              void* d_out, int out_size, void* d_ws, size_t ws_size,
                              hipStream_t stream) {
    const float* x    = (const float*)d_in[0];
    const int*   msrc = (const int*)d_in[1];
    const int*   mdst = (const int*)d_in[2];
    const int*   psrc = (const int*)d_in[3];
    const int*   pdst = (const int*)d_in[4];
    const int*   nsrc = (const int*)d_in[5];
    const int*   ndst = (const int*)d_in[6];
    const float* W1s  = (const float*)d_in[7];
    const float* W1n  = (const float*)d_in[8];
    const float* b1   = (const float*)d_in[9];
    const float* W2s  = (const float*)d_in[10];
    const float* W2n  = (const float*)d_in[11];
    const float* b2   = (const float*)d_in[12];
    const float* wp   = (const float*)d_in[13];
    const float* bp   = (const float*)d_in[14];

    char* ws = (char*)d_ws;
    int*   cnt      = (int*)ws + I_CNT;
    int*   rowstart = (int*)ws + I_ROW;
    int*   cursor   = (int*)ws + I_CUR;
    int*   csr_src  = (int*)ws + I_CSR;
    bf16*  xb    = (bf16*)(ws + B_XB);
    bf16*  agg1b = (bf16*)(ws + B_AGG1);
    bf16*  h1b   = (bf16*)(ws + B_H1);
    bf16*  z2b   = (bf16*)(ws + B_Z2);
    float* h2s   = (float*)(ws + B_H2S);
    bf16*  Wt1   = (bf16*)(ws + B_WT1);
    bf16*  Wt2   = (bf16*)(ws + B_WT2);
    float* p     = (float*)(ws + B_P);
    float* q     = (float*)(ws + B_Q);
    float* out   = (float*)d_out;

    hipMemsetAsync(cnt, 0, 50176 * sizeof(int), stream);

    count_kernel<<<(EM + 255) / 256, 256, 0, stream>>>(mdst, cnt, EM);
    scan_kernel<<<1, 1024, 0, stream>>>(cnt, rowstart, cursor);
    bucket_kernel<<<(EM + 255) / 256, 256, 0, stream>>>(msrc, mdst, cursor, csr_src, EM);

    convx_kernel<<<6250, 256, 0, stream>>>(x, xb);
    convw_kernel<<<256, 256, 0, stream>>>(W1s, W1n, W2n, W2s, Wt1, Wt2);

    gather1_kernel<<<(NN * 64 + 255) / 256, 256, 0, stream>>>(xb, rowstart, csr_src, agg1b);
    gemm1_kernel<<<(NN + 63) / 64, 256, 0, stream>>>(xb, agg1b, Wt1, b1, h1b);
    gemm2_kernel<<<(NN + 63) / 64, 256, 0, stream>>>(h1b, Wt2, b2, z2b, h2s);
    gather2_kernel<<<(NN * 64 + 255) / 256, 256, 0, stream>>>(z2b, rowstart, csr_src,
                                                              h2s, wp, p, q);
    score_kernel<<<(EPOS + ENEG + 255) / 256, 256, 0, stream>>>(
        psrc, pdst, nsrc, ndst, p, q, bp, out);
}

// Round 4
// 429.244 us; speedup vs baseline: 7.3602x; 1.2529x over previous
//
#include <hip/hip_runtime.h>

// GraphSAGE 2-layer + edge scorer, MI355X.
// R4: single-block scan (126 us, 1 CU) -> 3-phase parallel scan (~10 us).
// Structure: CSR build -> convert x,W -> gather1 -> gemm1(relu) ->
// gemm2(z2 bf16 + h2self fp32) -> gather2+epilogue(p,q) -> score.
// Rewrites kept: mean(h1[src])@W2n == mean((h1@W2n)[src]); h2 never
// materialized: score = p[src] + q[dst] + bp.

#define NN 50000
#define EM 800000
#define EPOS 200000
#define ENEG 200000
#define NB 196            // scan blocks: 196*256 = 50176 >= NN

typedef __bf16 bf16;
typedef bf16 bf16x2 __attribute__((ext_vector_type(2)));
typedef bf16 bf16x4 __attribute__((ext_vector_type(4)));
typedef bf16 bf16x8 __attribute__((ext_vector_type(8)));
typedef float floatx4 __attribute__((ext_vector_type(4)));

// ---- workspace word/byte offsets ----
#define I_CNT 0              // 50176 ints
#define I_ROW 50176          // 50432 ints
#define I_CUR 100608         // 50176 ints
#define I_BSUM 150784        // 256 ints
#define I_BOFF 151040        // 256 ints
#define I_CSR 151296         // 800000 ints -> ints end at word 951296
#define B_XB   3808256       // bytes; 6.4M bf16 (12.8 MB)
#define B_AGG1 16608256      // 6.4M bf16
#define B_H1   29408256      // 12.8M bf16 (25.6 MB)
#define B_Z2   55008256      // 6.4M bf16
#define B_H2S  67808256      // 6.4M fp32 (25.6 MB)
#define B_WT1  93408256      // 65536 bf16
#define B_WT2  93539328      // 65536 bf16
#define B_P    93670400      // 50176 fp32
#define B_Q    93871104      // 50176 fp32
// end ~94.1 MB

__global__ __launch_bounds__(256) void count_kernel(const int* __restrict__ dst,
                                                    int* __restrict__ cnt, int n) {
    int i = blockIdx.x * blockDim.x + threadIdx.x;
    if (i < n) atomicAdd(&cnt[dst[i]], 1);
}

// phase 1: per-block sums of cnt
__global__ __launch_bounds__(256) void scan1_kernel(const int* __restrict__ cnt,
                                                    int* __restrict__ bsum) {
    __shared__ int s[256];
    int t = threadIdx.x;
    int i = blockIdx.x * 256 + t;
    s[t] = (i < NN) ? cnt[i] : 0;
    __syncthreads();
    for (int o = 128; o > 0; o >>= 1) {
        if (t < o) s[t] += s[t + o];
        __syncthreads();
    }
    if (t == 0) bsum[blockIdx.x] = s[0];
}

// phase 2: exclusive scan of the NB block sums (single 256-thread block)
__global__ __launch_bounds__(256) void scan2_kernel(const int* __restrict__ bsum,
                                                    int* __restrict__ boff) {
    __shared__ int s[256];
    int t = threadIdx.x;
    s[t] = (t < NB) ? bsum[t] : 0;
    __syncthreads();
    for (int o = 1; o < 256; o <<= 1) {
        int u = (t >= o) ? s[t - o] : 0;
        __syncthreads();
        s[t] += u;
        __syncthreads();
    }
    if (t < NB) boff[t] = (t == 0) ? 0 : s[t - 1];
}

// phase 3: local inclusive scan + block offset -> rowstart, cursor
__global__ __launch_bounds__(256) void scan3_kernel(const int* __restrict__ cnt,
                                                    const int* __restrict__ boff,
                                                    int* __restrict__ rowstart,
                                                    int* __restrict__ cursor) {
    __shared__ int s[256];
    int t = threadIdx.x;
    int i = blockIdx.x * 256 + t;
    int v = (i < NN) ? cnt[i] : 0;
    s[t] = v;
    __syncthreads();
    for (int o = 1; o < 256; o <<= 1) {
        int u = (t >= o) ? s[t - o] : 0;
        __syncthreads();
        s[t] += u;
        __syncthreads();
    }
    int excl = boff[blockIdx.x] + s[t] - v;
    if (i < NN) {
        rowstart[i] = excl;
        cursor[i] = excl;
    }
    if (i == NN - 1) rowstart[NN] = EM;
}

__global__ __launch_bounds__(256) void bucket_kernel(const int* __restrict__ src,
                                                     const int* __restrict__ dst,
                                                     int* __restrict__ cursor,
                                                     int* __restrict__ csr_src, int n) {
    int e = blockIdx.x * blockDim.x + threadIdx.x;
    if (e < n) {
        int d = dst[e];
        int pos = atomicAdd(&cursor[d], 1);
        csr_src[pos] = src[e];
    }
}

// x fp32 -> bf16, 4 elems/thread
__global__ __launch_bounds__(256) void convx_kernel(const float* __restrict__ x,
                                                    bf16* __restrict__ xb) {
    int i = blockIdx.x * 256 + threadIdx.x;
    if (i >= NN * 128 / 4) return;
    float4 v = ((const float4*)x)[i];
    bf16x4 o;
    o[0] = (bf16)v.x; o[1] = (bf16)v.y; o[2] = (bf16)v.z; o[3] = (bf16)v.w;
    *(bf16x4*)(xb + (size_t)i * 4) = o;
}

// Wt1[n][k] = k<128 ? W1s[k][n] : W1n[k-128][n]   (256x256, n-major)
// Wt2[n][k] = n<128 ? W2n[k][n] : W2s[k][n-128]
__global__ __launch_bounds__(256) void convw_kernel(
    const float* __restrict__ W1s, const float* __restrict__ W1n,
    const float* __restrict__ W2n, const float* __restrict__ W2s,
    bf16* __restrict__ Wt1, bf16* __restrict__ Wt2) {
    int i = blockIdx.x * 256 + threadIdx.x;
    if (i >= 65536) return;
    int n = i >> 8, k = i & 255;
    float w1 = (k < 128) ? W1s[k * 256 + n] : W1n[(k - 128) * 256 + n];
    Wt1[i] = (bf16)w1;
    float w2 = (n < 128) ? W2n[k * 128 + n] : W2s[k * 128 + (n - 128)];
    Wt2[i] = (bf16)w2;
}

// one wave per node: mean of bf16 feat rows over CSR bucket -> bf16 agg
__global__ __launch_bounds__(256) void gather1_kernel(const bf16* __restrict__ feat,
                                                      const int* __restrict__ rowstart,
                                                      const int* __restrict__ csr,
                                                      bf16* __restrict__ agg) {
    int node = (blockIdx.x * 256 + threadIdx.x) >> 6;
    if (node >= NN) return;
    int lane = threadIdx.x & 63;
    int c = lane * 2;
    int beg = rowstart[node], end = rowstart[node + 1];
    float ax = 0.f, ay = 0.f;
    int i = beg;
    for (; i + 3 < end; i += 4) {
        int s0 = csr[i], s1 = csr[i + 1], s2 = csr[i + 2], s3 = csr[i + 3];
        bf16x2 v0 = *(const bf16x2*)(feat + (size_t)s0 * 128 + c);
        bf16x2 v1 = *(const bf16x2*)(feat + (size_t)s1 * 128 + c);
        bf16x2 v2 = *(const bf16x2*)(feat + (size_t)s2 * 128 + c);
        bf16x2 v3 = *(const bf16x2*)(feat + (size_t)s3 * 128 + c);
        ax += (float)v0[0] + (float)v1[0] + (float)v2[0] + (float)v3[0];
        ay += (float)v0[1] + (float)v1[1] + (float)v2[1] + (float)v3[1];
    }
    for (; i < end; ++i) {
        int s = csr[i];
        bf16x2 v = *(const bf16x2*)(feat + (size_t)s * 128 + c);
        ax += (float)v[0];
        ay += (float)v[1];
    }
    int deg = end - beg;
    float inv = 1.0f / (float)(deg > 0 ? deg : 1);
    bf16x2 o;
    o[0] = (bf16)(ax * inv);
    o[1] = (bf16)(ay * inv);
    *(bf16x2*)(agg + (size_t)node * 128 + c) = o;
}

// h1 = relu([xb | agg1b] @ Wt1^T + b1) -> bf16.  M=50000, K=256, N=256.
__global__ __launch_bounds__(256) void gemm1_kernel(
    const bf16* __restrict__ xb, const bf16* __restrict__ aggb,
    const bf16* __restrict__ Wt, const float* __restrict__ b1,
    bf16* __restrict__ h1b) {
    int wave = threadIdx.x >> 6;
    int lane = threadIdx.x & 63;
    int m0 = blockIdx.x * 64 + wave * 16;
    int r = lane & 15, quad = lane >> 4;
    int row = m0 + r; if (row >= NN) row = NN - 1;
    floatx4 acc[16];
#pragma unroll
    for (int t = 0; t < 16; ++t) acc[t] = (floatx4){0.f, 0.f, 0.f, 0.f};
    for (int k0 = 0; k0 < 256; k0 += 32) {
        int k = k0 + quad * 8;
        const bf16* abase = (k < 128) ? (xb + (size_t)row * 128 + k)
                                      : (aggb + (size_t)row * 128 + (k - 128));
        bf16x8 a = *(const bf16x8*)abase;
#pragma unroll
        for (int t = 0; t < 16; ++t) {
            bf16x8 b = *(const bf16x8*)(Wt + (size_t)(t * 16 + r) * 256 + k);
            acc[t] = __builtin_amdgcn_mfma_f32_16x16x32_bf16(a, b, acc[t], 0, 0, 0);
        }
    }
    int mbase = m0 + quad * 4;
#pragma unroll
    for (int t = 0; t < 16; ++t) {
        int col = t * 16 + r;
        float bb = b1[col];
#pragma unroll
        for (int rr = 0; rr < 4; ++rr) {
            int gm = mbase + rr;
            if (gm < NN) {
                float v = acc[t][rr] + bb;
                v = v > 0.f ? v : 0.f;
                h1b[(size_t)gm * 256 + col] = (bf16)v;
            }
        }
    }
}

// [z2 | h2self] = h1b @ Wt2^T (+b2 on right half). z2 bf16, h2self fp32.
__global__ __launch_bounds__(256) void gemm2_kernel(
    const bf16* __restrict__ h1b, const bf16* __restrict__ Wt,
    const float* __restrict__ b2, bf16* __restrict__ z2b,
    float* __restrict__ h2s) {
    int wave = threadIdx.x >> 6;
    int lane = threadIdx.x & 63;
    int m0 = blockIdx.x * 64 + wave * 16;
    int r = lane & 15, quad = lane >> 4;
    int row = m0 + r; if (row >= NN) row = NN - 1;
    floatx4 acc[16];
#pragma unroll
    for (int t = 0; t < 16; ++t) acc[t] = (floatx4){0.f, 0.f, 0.f, 0.f};
    for (int k0 = 0; k0 < 256; k0 += 32) {
        int k = k0 + quad * 8;
        bf16x8 a = *(const bf16x8*)(h1b + (size_t)row * 256 + k);
#pragma unroll
        for (int t = 0; t < 16; ++t) {
            bf16x8 b = *(const bf16x8*)(Wt + (size_t)(t * 16 + r) * 256 + k);
            acc[t] = __builtin_amdgcn_mfma_f32_16x16x32_bf16(a, b, acc[t], 0, 0, 0);
        }
    }
    int mbase = m0 + quad * 4;
#pragma unroll
    for (int t = 0; t < 8; ++t) {   // left half -> z2 (bf16)
        int col = t * 16 + r;
#pragma unroll
        for (int rr = 0; rr < 4; ++rr) {
            int gm = mbase + rr;
            if (gm < NN) z2b[(size_t)gm * 128 + col] = (bf16)acc[t][rr];
        }
    }
#pragma unroll
    for (int t = 8; t < 16; ++t) {  // right half -> h2self + b2 (fp32)
        int col = t * 16 + r - 128;
        float bb = b2[col];
#pragma unroll
        for (int rr = 0; rr < 4; ++rr) {
            int gm = mbase + rr;
            if (gm < NN) h2s[(size_t)gm * 128 + col] = acc[t + 0][rr] + bb;
        }
    }
}

// gather2 + epilogue: mean(z2[neigh]) + h2self -> h2; p = h2.wp[:128], q = h2.wp[128:]
__global__ __launch_bounds__(256) void gather2_kernel(
    const bf16* __restrict__ z2b, const int* __restrict__ rowstart,
    const int* __restrict__ csr, const float* __restrict__ h2s,
    const float* __restrict__ wp, float* __restrict__ p, float* __restrict__ q) {
    int node = (blockIdx.x * 256 + threadIdx.x) >> 6;
    if (node >= NN) return;
    int lane = threadIdx.x & 63;
    int c = lane * 2;
    int beg = rowstart[node], end = rowstart[node + 1];
    float ax = 0.f, ay = 0.f;
    int i = beg;
    for (; i + 3 < end; i += 4) {
        int s0 = csr[i], s1 = csr[i + 1], s2 = csr[i + 2], s3 = csr[i + 3];
        bf16x2 v0 = *(const bf16x2*)(z2b + (size_t)s0 * 128 + c);
        bf16x2 v1 = *(const bf16x2*)(z2b + (size_t)s1 * 128 + c);
        bf16x2 v2 = *(const bf16x2*)(z2b + (size_t)s2 * 128 + c);
        bf16x2 v3 = *(const bf16x2*)(z2b + (size_t)s3 * 128 + c);
        ax += (float)v0[0] + (float)v1[0] + (float)v2[0] + (float)v3[0];
        ay += (float)v0[1] + (float)v1[1] + (float)v2[1] + (float)v3[1];
    }
    for (; i < end; ++i) {
        int s = csr[i];
        bf16x2 v = *(const bf16x2*)(z2b + (size_t)s * 128 + c);
        ax += (float)v[0];
        ay += (float)v[1];
    }
    int deg = end - beg;
    float inv = 1.0f / (float)(deg > 0 ? deg : 1);
    float v0 = h2s[(size_t)node * 128 + c] + ax * inv;      // b2 already added
    float v1 = h2s[(size_t)node * 128 + c + 1] + ay * inv;
    float pa = v0 * wp[c] + v1 * wp[c + 1];
    float qa = v0 * wp[128 + c] + v1 * wp[129 + c];
#pragma unroll
    for (int off = 32; off > 0; off >>= 1) {
        pa += __shfl_down(pa, off);
        qa += __shfl_down(qa, off);
    }
    if (lane == 0) {
        p[node] = pa;
        q[node] = qa;
    }
}

__global__ __launch_bounds__(256) void score_kernel(
    const int* __restrict__ psrc, const int* __restrict__ pdst,
    const int* __restrict__ nsrc, const int* __restrict__ ndst,
    const float* __restrict__ p, const float* __restrict__ q,
    const float* __restrict__ bp, float* __restrict__ out) {
    int i = blockIdx.x * blockDim.x + threadIdx.x;
    float b = bp[0];
    if (i < EPOS) {
        out[i] = p[psrc[i]] + q[pdst[i]] + b;
    } else if (i < EPOS + ENEG) {
        int j = i - EPOS;
        out[i] = p[nsrc[j]] + q[ndst[j]] + b;
    }
}

extern "C" void kernel_launch(void* const* d_in, const int* in_sizes, int n_in,
                              void* d_out, int out_size, void* d_ws, size_t ws_size,
                              hipStream_t stream) {
    const float* x    = (const float*)d_in[0];
    const int*   msrc = (const int*)d_in[1];
    const int*   mdst = (const int*)d_in[2];
    const int*   psrc = (const int*)d_in[3];
    const int*   pdst = (const int*)d_in[4];
    const int*   nsrc = (const int*)d_in[5];
    const int*   ndst = (const int*)d_in[6];
    const float* W1s  = (const float*)d_in[7];
    const float* W1n  = (const float*)d_in[8];
    const float* b1   = (const float*)d_in[9];
    const float* W2s  = (const float*)d_in[10];
    const float* W2n  = (const float*)d_in[11];
    const float* b2   = (const float*)d_in[12];
    const float* wp   = (const float*)d_in[13];
    const float* bp   = (const float*)d_in[14];

    char* ws = (char*)d_ws;
    int*   cnt      = (int*)ws + I_CNT;
    int*   rowstart = (int*)ws + I_ROW;
    int*   cursor   = (int*)ws + I_CUR;
    int*   bsum     = (int*)ws + I_BSUM;
    int*   boff     = (int*)ws + I_BOFF;
    int*   csr_src  = (int*)ws + I_CSR;
    bf16*  xb    = (bf16*)(ws + B_XB);
    bf16*  agg1b = (bf16*)(ws + B_AGG1);
    bf16*  h1b   = (bf16*)(ws + B_H1);
    bf16*  z2b   = (bf16*)(ws + B_Z2);
    float* h2s   = (float*)(ws + B_H2S);
    bf16*  Wt1   = (bf16*)(ws + B_WT1);
    bf16*  Wt2   = (bf16*)(ws + B_WT2);
    float* p     = (float*)(ws + B_P);
    float* q     = (float*)(ws + B_Q);
    float* out   = (float*)d_out;

    hipMemsetAsync(cnt, 0, 50176 * sizeof(int), stream);

    count_kernel<<<(EM + 255) / 256, 256, 0, stream>>>(mdst, cnt, EM);
    scan1_kernel<<<NB, 256, 0, stream>>>(cnt, bsum);
    scan2_kernel<<<1, 256, 0, stream>>>(bsum, boff);
    scan3_kernel<<<NB, 256, 0, stream>>>(cnt, boff, rowstart, cursor);
    bucket_kernel<<<(EM + 255) / 256, 256, 0, stream>>>(msrc, mdst, cursor, csr_src, EM);

    convx_kernel<<<6250, 256, 0, stream>>>(x, xb);
    convw_kernel<<<256, 256, 0, stream>>>(W1s, W1n, W2n, W2s, Wt1, Wt2);

    gather1_kernel<<<(NN * 64 + 255) / 256, 256, 0, stream>>>(xb, rowstart, csr_src, agg1b);
    gemm1_kernel<<<(NN + 63) / 64, 256, 0, stream>>>(xb, agg1b, Wt1, b1, h1b);
    gemm2_kernel<<<(NN + 63) / 64, 256, 0, stream>>>(h1b, Wt2, b2, z2b, h2s);
    gather2_kernel<<<(NN * 64 + 255) / 256, 256, 0, stream>>>(z2b, rowstart, csr_src,
                                                              h2s, wp, p, q);
    score_kernel<<<(EPOS + ENEG + 255) / 256, 256, 0, stream>>>(
        psrc, pdst, nsrc, ndst, p, q, bp, out);
}

// Round 5
// 326.273 us; speedup vs baseline: 9.6831x; 1.3156x over previous
//
#include <hip/hip_runtime.h>

// GraphSAGE 2-layer + edge scorer, MI355X.
// R5: GEMMs restructured -> B (weights, 128 KB) held in registers per wave
// (128 VGPRs), A streamed over row-tiles. Kills the per-K-step B re-fetch
// that made R4's gemm latency-bound (MfmaUtil 2.9%).
// Rewrites kept: mean(h1[src])@W2n == mean((h1@W2n)[src]); h2 never
// materialized: score = p[src] + q[dst] + bp.

#define NN 50000
#define EM 800000
#define EPOS 200000
#define ENEG 200000
#define NB 196            // scan blocks: 196*256 = 50176 >= NN
#define MTILES 3125       // 50000 / 16 exactly
#define GEMM_GRID 512

typedef __bf16 bf16;
typedef bf16 bf16x2 __attribute__((ext_vector_type(2)));
typedef bf16 bf16x4 __attribute__((ext_vector_type(4)));
typedef bf16 bf16x8 __attribute__((ext_vector_type(8)));
typedef float floatx4 __attribute__((ext_vector_type(4)));

// ---- workspace word/byte offsets ----
#define I_CNT 0              // 50176 ints
#define I_ROW 50176          // 50432 ints
#define I_CUR 100608         // 50176 ints
#define I_BSUM 150784        // 256 ints
#define I_BOFF 151040        // 256 ints
#define I_CSR 151296         // 800000 ints
#define B_XB   3808256       // bytes; 6.4M bf16 (12.8 MB)
#define B_AGG1 16608256      // 6.4M bf16
#define B_H1   29408256      // 12.8M bf16 (25.6 MB)
#define B_Z2   55008256      // 6.4M bf16
#define B_H2S  67808256      // 6.4M fp32 (25.6 MB)
#define B_WT1  93408256      // 65536 bf16
#define B_WT2  93539328      // 65536 bf16
#define B_P    93670400      // 50176 fp32
#define B_Q    93871104      // 50176 fp32

__global__ __launch_bounds__(256) void count_kernel(const int* __restrict__ dst,
                                                    int* __restrict__ cnt, int n) {
    int i = blockIdx.x * blockDim.x + threadIdx.x;
    if (i < n) atomicAdd(&cnt[dst[i]], 1);
}

__global__ __launch_bounds__(256) void scan1_kernel(const int* __restrict__ cnt,
                                                    int* __restrict__ bsum) {
    __shared__ int s[256];
    int t = threadIdx.x;
    int i = blockIdx.x * 256 + t;
    s[t] = (i < NN) ? cnt[i] : 0;
    __syncthreads();
    for (int o = 128; o > 0; o >>= 1) {
        if (t < o) s[t] += s[t + o];
        __syncthreads();
    }
    if (t == 0) bsum[blockIdx.x] = s[0];
}

__global__ __launch_bounds__(256) void scan2_kernel(const int* __restrict__ bsum,
                                                    int* __restrict__ boff) {
    __shared__ int s[256];
    int t = threadIdx.x;
    s[t] = (t < NB) ? bsum[t] : 0;
    __syncthreads();
    for (int o = 1; o < 256; o <<= 1) {
        int u = (t >= o) ? s[t - o] : 0;
        __syncthreads();
        s[t] += u;
        __syncthreads();
    }
    if (t < NB) boff[t] = (t == 0) ? 0 : s[t - 1];
}

__global__ __launch_bounds__(256) void scan3_kernel(const int* __restrict__ cnt,
                                                    const int* __restrict__ boff,
                                                    int* __restrict__ rowstart,
                                                    int* __restrict__ cursor) {
    __shared__ int s[256];
    int t = threadIdx.x;
    int i = blockIdx.x * 256 + t;
    int v = (i < NN) ? cnt[i] : 0;
    s[t] = v;
    __syncthreads();
    for (int o = 1; o < 256; o <<= 1) {
        int u = (t >= o) ? s[t - o] : 0;
        __syncthreads();
        s[t] += u;
        __syncthreads();
    }
    int excl = boff[blockIdx.x] + s[t] - v;
    if (i < NN) {
        rowstart[i] = excl;
        cursor[i] = excl;
    }
    if (i == NN - 1) rowstart[NN] = EM;
}

__global__ __launch_bounds__(256) void bucket_kernel(const int* __restrict__ src,
                                                     const int* __restrict__ dst,
                                                     int* __restrict__ cursor,
                                                     int* __restrict__ csr_src, int n) {
    int e = blockIdx.x * blockDim.x + threadIdx.x;
    if (e < n) {
        int d = dst[e];
        int pos = atomicAdd(&cursor[d], 1);
        csr_src[pos] = src[e];
    }
}

__global__ __launch_bounds__(256) void convx_kernel(const float* __restrict__ x,
                                                    bf16* __restrict__ xb) {
    int i = blockIdx.x * 256 + threadIdx.x;
    if (i >= NN * 128 / 4) return;
    float4 v = ((const float4*)x)[i];
    bf16x4 o;
    o[0] = (bf16)v.x; o[1] = (bf16)v.y; o[2] = (bf16)v.z; o[3] = (bf16)v.w;
    *(bf16x4*)(xb + (size_t)i * 4) = o;
}

// Wt1[n][k] = k<128 ? W1s[k][n] : W1n[k-128][n]   (256x256, n-major)
// Wt2[n][k] = n<128 ? W2n[k][n] : W2s[k][n-128]
__global__ __launch_bounds__(256) void convw_kernel(
    const float* __restrict__ W1s, const float* __restrict__ W1n,
    const float* __restrict__ W2n, const float* __restrict__ W2s,
    bf16* __restrict__ Wt1, bf16* __restrict__ Wt2) {
    int i = blockIdx.x * 256 + threadIdx.x;
    if (i >= 65536) return;
    int n = i >> 8, k = i & 255;
    float w1 = (k < 128) ? W1s[k * 256 + n] : W1n[(k - 128) * 256 + n];
    Wt1[i] = (bf16)w1;
    float w2 = (n < 128) ? W2n[k * 128 + n] : W2s[k * 128 + (n - 128)];
    Wt2[i] = (bf16)w2;
}

// one wave per node: mean of bf16 feat rows over CSR bucket -> bf16 agg
__global__ __launch_bounds__(256) void gather1_kernel(const bf16* __restrict__ feat,
                                                      const int* __restrict__ rowstart,
                                                      const int* __restrict__ csr,
                                                      bf16* __restrict__ agg) {
    int node = (blockIdx.x * 256 + threadIdx.x) >> 6;
    if (node >= NN) return;
    int lane = threadIdx.x & 63;
    int c = lane * 2;
    int beg = rowstart[node], end = rowstart[node + 1];
    float ax = 0.f, ay = 0.f;
    int i = beg;
    for (; i + 7 < end; i += 8) {
        float lx = 0.f, ly = 0.f;
#pragma unroll
        for (int u = 0; u < 8; ++u) {
            int s = csr[i + u];
            bf16x2 v = *(const bf16x2*)(feat + (size_t)s * 128 + c);
            lx += (float)v[0];
            ly += (float)v[1];
        }
        ax += lx; ay += ly;
    }
    for (; i < end; ++i) {
        int s = csr[i];
        bf16x2 v = *(const bf16x2*)(feat + (size_t)s * 128 + c);
        ax += (float)v[0];
        ay += (float)v[1];
    }
    int deg = end - beg;
    float inv = 1.0f / (float)(deg > 0 ? deg : 1);
    bf16x2 o;
    o[0] = (bf16)(ax * inv);
    o[1] = (bf16)(ay * inv);
    *(bf16x2*)(agg + (size_t)node * 128 + c) = o;
}

// h1 = relu([xb | agg1b] @ Wt1^T + b1) -> bf16.  M=50000, K=256, N=256.
// Wave w holds B-fragments for cols [w*64, w*64+64) in registers (128 VGPRs),
// streams A over row-tiles (grid-stride).
__global__ __launch_bounds__(256) void gemm1_kernel(
    const bf16* __restrict__ xb, const bf16* __restrict__ aggb,
    const bf16* __restrict__ Wt, const float* __restrict__ b1,
    bf16* __restrict__ h1b) {
    int w = threadIdx.x >> 6;
    int lane = threadIdx.x & 63;
    int r = lane & 15, quad = lane >> 4;
    int colbase = w * 64;

    bf16x8 bf[4][8];
#pragma unroll
    for (int t = 0; t < 4; ++t)
#pragma unroll
        for (int kk = 0; kk < 8; ++kk)
            bf[t][kk] = *(const bf16x8*)(Wt + (size_t)(colbase + t * 16 + r) * 256
                                         + kk * 32 + quad * 8);
    float bb[4];
#pragma unroll
    for (int t = 0; t < 4; ++t) bb[t] = b1[colbase + t * 16 + r];

    for (int tile = blockIdx.x; tile < MTILES; tile += GEMM_GRID) {
        int m0 = tile * 16;
        int row = m0 + r;
        bf16x8 a[8];
#pragma unroll
        for (int kk = 0; kk < 4; ++kk)
            a[kk] = *(const bf16x8*)(xb + (size_t)row * 128 + kk * 32 + quad * 8);
#pragma unroll
        for (int kk = 4; kk < 8; ++kk)
            a[kk] = *(const bf16x8*)(aggb + (size_t)row * 128 + (kk - 4) * 32 + quad * 8);
        floatx4 acc[4];
#pragma unroll
        for (int t = 0; t < 4; ++t) acc[t] = (floatx4){0.f, 0.f, 0.f, 0.f};
#pragma unroll
        for (int kk = 0; kk < 8; ++kk)
#pragma unroll
            for (int t = 0; t < 4; ++t)
                acc[t] = __builtin_amdgcn_mfma_f32_16x16x32_bf16(a[kk], bf[t][kk],
                                                                 acc[t], 0, 0, 0);
        int mb = m0 + quad * 4;
#pragma unroll
        for (int t = 0; t < 4; ++t) {
            int col = colbase + t * 16 + r;
#pragma unroll
            for (int rr = 0; rr < 4; ++rr) {
                float v = acc[t][rr] + bb[t];
                v = v > 0.f ? v : 0.f;
                h1b[(size_t)(mb + rr) * 256 + col] = (bf16)v;
            }
        }
    }
}

// [z2 | h2self] = h1b @ Wt2^T. Waves 0-1 -> z2 (bf16), waves 2-3 -> h2self+b2 (fp32).
__global__ __launch_bounds__(256) void gemm2_kernel(
    const bf16* __restrict__ h1b, const bf16* __restrict__ Wt,
    const float* __restrict__ b2, bf16* __restrict__ z2b,
    float* __restrict__ h2s) {
    int w = threadIdx.x >> 6;
    int lane = threadIdx.x & 63;
    int r = lane & 15, quad = lane >> 4;
    int colbase = w * 64;

    bf16x8 bf[4][8];
#pragma unroll
    for (int t = 0; t < 4; ++t)
#pragma unroll
        for (int kk = 0; kk < 8; ++kk)
            bf[t][kk] = *(const bf16x8*)(Wt + (size_t)(colbase + t * 16 + r) * 256
                                         + kk * 32 + quad * 8);
    float bb[4];
#pragma unroll
    for (int t = 0; t < 4; ++t)
        bb[t] = (w >= 2) ? b2[colbase - 128 + t * 16 + r] : 0.f;

    for (int tile = blockIdx.x; tile < MTILES; tile += GEMM_GRID) {
        int m0 = tile * 16;
        int row = m0 + r;
        bf16x8 a[8];
#pragma unroll
        for (int kk = 0; kk < 8; ++kk)
            a[kk] = *(const bf16x8*)(h1b + (size_t)row * 256 + kk * 32 + quad * 8);
        floatx4 acc[4];
#pragma unroll
        for (int t = 0; t < 4; ++t) acc[t] = (floatx4){0.f, 0.f, 0.f, 0.f};
#pragma unroll
        for (int kk = 0; kk < 8; ++kk)
#pragma unroll
            for (int t = 0; t < 4; ++t)
                acc[t] = __builtin_amdgcn_mfma_f32_16x16x32_bf16(a[kk], bf[t][kk],
                                                                 acc[t], 0, 0, 0);
        int mb = m0 + quad * 4;
        if (w < 2) {
#pragma unroll
            for (int t = 0; t < 4; ++t) {
                int col = colbase + t * 16 + r;
#pragma unroll
                for (int rr = 0; rr < 4; ++rr)
                    z2b[(size_t)(mb + rr) * 128 + col] = (bf16)acc[t][rr];
            }
        } else {
#pragma unroll
            for (int t = 0; t < 4; ++t) {
                int col = colbase - 128 + t * 16 + r;
#pragma unroll
                for (int rr = 0; rr < 4; ++rr)
                    h2s[(size_t)(mb + rr) * 128 + col] = acc[t][rr] + bb[t];
            }
        }
    }
}

// gather2 + epilogue: mean(z2[neigh]) + h2self -> h2; p = h2.wp[:128], q = h2.wp[128:]
__global__ __launch_bounds__(256) void gather2_kernel(
    const bf16* __restrict__ z2b, const int* __restrict__ rowstart,
    const int* __restrict__ csr, const float* __restrict__ h2s,
    const float* __restrict__ wp, float* __restrict__ p, float* __restrict__ q) {
    int node = (blockIdx.x * 256 + threadIdx.x) >> 6;
    if (node >= NN) return;
    int lane = threadIdx.x & 63;
    int c = lane * 2;
    int beg = rowstart[node], end = rowstart[node + 1];
    float ax = 0.f, ay = 0.f;
    int i = beg;
    for (; i + 7 < end; i += 8) {
        float lx = 0.f, ly = 0.f;
#pragma unroll
        for (int u = 0; u < 8; ++u) {
            int s = csr[i + u];
            bf16x2 v = *(const bf16x2*)(z2b + (size_t)s * 128 + c);
            lx += (float)v[0];
            ly += (float)v[1];
        }
        ax += lx; ay += ly;
    }
    for (; i < end; ++i) {
        int s = csr[i];
        bf16x2 v = *(const bf16x2*)(z2b + (size_t)s * 128 + c);
        ax += (float)v[0];
        ay += (float)v[1];
    }
    int deg = end - beg;
    float inv = 1.0f / (float)(deg > 0 ? deg : 1);
    float v0 = h2s[(size_t)node * 128 + c] + ax * inv;      // b2 already added
    float v1 = h2s[(size_t)node * 128 + c + 1] + ay * inv;
    float pa = v0 * wp[c] + v1 * wp[c + 1];
    float qa = v0 * wp[128 + c] + v1 * wp[129 + c];
#pragma unroll
    for (int off = 32; off > 0; off >>= 1) {
        pa += __shfl_down(pa, off);
        qa += __shfl_down(qa, off);
    }
    if (lane == 0) {
        p[node] = pa;
        q[node] = qa;
    }
}

__global__ __launch_bounds__(256) void score_kernel(
    const int* __restrict__ psrc, const int* __restrict__ pdst,
    const int* __restrict__ nsrc, const int* __restrict__ ndst,
    const float* __restrict__ p, const float* __restrict__ q,
    const float* __restrict__ bp, float* __restrict__ out) {
    int i = blockIdx.x * blockDim.x + threadIdx.x;
    float b = bp[0];
    if (i < EPOS) {
        out[i] = p[psrc[i]] + q[pdst[i]] + b;
    } else if (i < EPOS + ENEG) {
        int j = i - EPOS;
        out[i] = p[nsrc[j]] + q[ndst[j]] + b;
    }
}

extern "C" void kernel_launch(void* const* d_in, const int* in_sizes, int n_in,
                              void* d_out, int out_size, void* d_ws, size_t ws_size,
                              hipStream_t stream) {
    const float* x    = (const float*)d_in[0];
    const int*   msrc = (const int*)d_in[1];
    const int*   mdst = (const int*)d_in[2];
    const int*   psrc = (const int*)d_in[3];
    const int*   pdst = (const int*)d_in[4];
    const int*   nsrc = (const int*)d_in[5];
    const int*   ndst = (const int*)d_in[6];
    const float* W1s  = (const float*)d_in[7];
    const float* W1n  = (const float*)d_in[8];
    const float* b1   = (const float*)d_in[9];
    const float* W2s  = (const float*)d_in[10];
    const float* W2n  = (const float*)d_in[11];
    const float* b2   = (const float*)d_in[12];
    const float* wp   = (const float*)d_in[13];
    const float* bp   = (const float*)d_in[14];

    char* ws = (char*)d_ws;
    int*   cnt      = (int*)ws + I_CNT;
    int*   rowstart = (int*)ws + I_ROW;
    int*   cursor   = (int*)ws + I_CUR;
    int*   bsum     = (int*)ws + I_BSUM;
    int*   boff     = (int*)ws + I_BOFF;
    int*   csr_src  = (int*)ws + I_CSR;
    bf16*  xb    = (bf16*)(ws + B_XB);
    bf16*  agg1b = (bf16*)(ws + B_AGG1);
    bf16*  h1b   = (bf16*)(ws + B_H1);
    bf16*  z2b   = (bf16*)(ws + B_Z2);
    float* h2s   = (float*)(ws + B_H2S);
    bf16*  Wt1   = (bf16*)(ws + B_WT1);
    bf16*  Wt2   = (bf16*)(ws + B_WT2);
    float* p     = (float*)(ws + B_P);
    float* q     = (float*)(ws + B_Q);
    float* out   = (float*)d_out;

    hipMemsetAsync(cnt, 0, 50176 * sizeof(int), stream);

    count_kernel<<<(EM + 255) / 256, 256, 0, stream>>>(mdst, cnt, EM);
    scan1_kernel<<<NB, 256, 0, stream>>>(cnt, bsum);
    scan2_kernel<<<1, 256, 0, stream>>>(bsum, boff);
    scan3_kernel<<<NB, 256, 0, stream>>>(cnt, boff, rowstart, cursor);
    bucket_kernel<<<(EM + 255) / 256, 256, 0, stream>>>(msrc, mdst, cursor, csr_src, EM);

    convx_kernel<<<6250, 256, 0, stream>>>(x, xb);
    convw_kernel<<<256, 256, 0, stream>>>(W1s, W1n, W2n, W2s, Wt1, Wt2);

    gather1_kernel<<<(NN * 64 + 255) / 256, 256, 0, stream>>>(xb, rowstart, csr_src, agg1b);
    gemm1_kernel<<<GEMM_GRID, 256, 0, stream>>>(xb, agg1b, Wt1, b1, h1b);
    gemm2_kernel<<<GEMM_GRID, 256, 0, stream>>>(h1b, Wt2, b2, z2b, h2s);
    gather2_kernel<<<(NN * 64 + 255) / 256, 256, 0, stream>>>(z2b, rowstart, csr_src,
                                                              h2s, wp, p, q);
    score_kernel<<<(EPOS + ENEG + 255) / 256, 256, 0, stream>>>(
        psrc, pdst, nsrc, ndst, p, q, bp, out);
}

// Round 6
// 303.515 us; speedup vs baseline: 10.4091x; 1.0750x over previous
//
#include <hip/hip_runtime.h>

// GraphSAGE 2-layer + edge scorer, MI355X.
// R6: bucket_kernel (800k scattered 4B stores -> 52 MB HBM writeback) replaced
// by two-pass binned CSR build: bin_kernel (LDS-sort 4096 edges by dst>>8,
// coalesced 8B-record flush into per-bucket regions sized from rowstart) +
// binsort_kernel (block-per-bucket, LDS cursors, writes own 16KB csr range).
// Rewrites kept: mean(h1[src])@W2n == mean((h1@W2n)[src]); h2 never
// materialized: score = p[src] + q[dst] + bp. GEMMs: B in registers (R5).

#define NN 50000
#define EM 800000
#define EPOS 200000
#define ENEG 200000
#define NB 196            // scan blocks / coarse buckets: 196*256 >= NN
#define RPB 4096          // records per bin_kernel block
#define MTILES 3125       // 50000 / 16 exactly
#define GEMM_GRID 512

typedef __bf16 bf16;
typedef bf16 bf16x2 __attribute__((ext_vector_type(2)));
typedef bf16 bf16x4 __attribute__((ext_vector_type(4)));
typedef bf16 bf16x8 __attribute__((ext_vector_type(8)));
typedef float floatx4 __attribute__((ext_vector_type(4)));

// ---- workspace offsets ----
// int-word offsets:
#define I_CNT  0             // 50176
#define I_ROW  50176         // 50432
#define I_BSUM 100608        // 256
#define I_BOFF 100864        // 256
#define I_CCUR 101120        // 256
#define I_CSR  101376        // 800000 -> ends word 901376
// byte offsets:
#define B_CREG 3605504       // 800000 * 8B records (6.4 MB), 8B-aligned
#define B_XB   10005504      // 6.4M bf16 (12.8 MB)
#define B_AGG1 22805504      // 6.4M bf16
#define B_H1   35605504      // 12.8M bf16 (25.6 MB)
#define B_Z2   61205504      // 6.4M bf16
#define B_H2S  74005504      // 6.4M fp32 (25.6 MB)
#define B_WT1  99605504      // 65536 bf16
#define B_WT2  99736576      // 65536 bf16
#define B_P    99867648      // 50176 fp32
#define B_Q    100068352     // 50176 fp32
// end ~100.3 MB

__global__ __launch_bounds__(256) void count_kernel(const int* __restrict__ dst,
                                                    int* __restrict__ cnt, int n) {
    int i = blockIdx.x * blockDim.x + threadIdx.x;
    if (i < n) atomicAdd(&cnt[dst[i]], 1);
}

__global__ __launch_bounds__(256) void scan1_kernel(const int* __restrict__ cnt,
                                                    int* __restrict__ bsum) {
    __shared__ int s[256];
    int t = threadIdx.x;
    int i = blockIdx.x * 256 + t;
    s[t] = (i < NN) ? cnt[i] : 0;
    __syncthreads();
    for (int o = 128; o > 0; o >>= 1) {
        if (t < o) s[t] += s[t + o];
        __syncthreads();
    }
    if (t == 0) bsum[blockIdx.x] = s[0];
}

__global__ __launch_bounds__(256) void scan2_kernel(const int* __restrict__ bsum,
                                                    int* __restrict__ boff) {
    __shared__ int s[256];
    int t = threadIdx.x;
    s[t] = (t < NB) ? bsum[t] : 0;
    __syncthreads();
    for (int o = 1; o < 256; o <<= 1) {
        int u = (t >= o) ? s[t - o] : 0;
        __syncthreads();
        s[t] += u;
        __syncthreads();
    }
    if (t < NB) boff[t] = (t == 0) ? 0 : s[t - 1];
}

// rowstart + per-coarse-bucket claim cursors (ccur[b] = boff[b] = rowstart[b*256])
__global__ __launch_bounds__(256) void scan3_kernel(const int* __restrict__ cnt,
                                                    const int* __restrict__ boff,
                                                    int* __restrict__ rowstart,
                                                    int* __restrict__ ccur) {
    __shared__ int s[256];
    int t = threadIdx.x;
    int i = blockIdx.x * 256 + t;
    int v = (i < NN) ? cnt[i] : 0;
    s[t] = v;
    __syncthreads();
    for (int o = 1; o < 256; o <<= 1) {
        int u = (t >= o) ? s[t - o] : 0;
        __syncthreads();
        s[t] += u;
        __syncthreads();
    }
    int excl = boff[blockIdx.x] + s[t] - v;
    if (i < NN) rowstart[i] = excl;
    if (i == NN - 1) rowstart[NN] = EM;
    if (t == 0) ccur[blockIdx.x] = boff[blockIdx.x];
}

// pass A: LDS-sort 4096 edges by coarse bucket (dst>>8), flush bucket-grouped
// 8B (src,dst) records into per-bucket regions of creg (regions = csr layout).
__global__ __launch_bounds__(256) void bin_kernel(const int* __restrict__ src,
                                                  const int* __restrict__ dst,
                                                  int* __restrict__ ccur,
                                                  unsigned long long* __restrict__ creg) {
    __shared__ int hist[NB];
    __shared__ int cnt2[NB];
    __shared__ int goff[NB];
    __shared__ int base[256];
    __shared__ unsigned long long sorted[RPB];
    int t = threadIdx.x;
    int e0 = blockIdx.x * RPB;
    int nrec = EM - e0; if (nrec > RPB) nrec = RPB;

    for (int i = t; i < NB; i += 256) { hist[i] = 0; cnt2[i] = 0; }
    __syncthreads();

    int myb[RPB / 256];
    unsigned long long myrec[RPB / 256];
#pragma unroll
    for (int j = 0; j < RPB / 256; ++j) {
        int idx = j * 256 + t;
        if (idx < nrec) {
            int s = src[e0 + idx], d = dst[e0 + idx];
            myb[j] = d >> 8;
            myrec[j] = ((unsigned long long)(unsigned)d << 32) | (unsigned)s;
            atomicAdd(&hist[myb[j]], 1);
        } else myb[j] = -1;
    }
    __syncthreads();

    base[t] = (t < NB) ? hist[t] : 0;
    __syncthreads();
    for (int o = 1; o < 256; o <<= 1) {   // inclusive scan; exclusive = base[b]-hist[b]
        int u = (t >= o) ? base[t - o] : 0;
        __syncthreads();
        base[t] += u;
        __syncthreads();
    }

    if (t < NB && hist[t] > 0) goff[t] = atomicAdd(&ccur[t], hist[t]);
#pragma unroll
    for (int j = 0; j < RPB / 256; ++j) {
        if (myb[j] >= 0) {
            int rk = atomicAdd(&cnt2[myb[j]], 1);
            sorted[base[myb[j]] - hist[myb[j]] + rk] = myrec[j];
        }
    }
    __syncthreads();

#pragma unroll
    for (int j = 0; j < RPB / 256; ++j) {
        int idx = j * 256 + t;
        if (idx < nrec) {
            unsigned long long rec = sorted[idx];
            int b = (int)(rec >> 40);            // d>>8 where d = rec>>32
            int exb = base[b] - hist[b];
            creg[(size_t)goff[b] + (idx - exb)] = rec;
        }
    }
}

// pass B: one block per coarse bucket; LDS cursors position edges within the
// bucket's exclusively-owned csr range. Writes coalesce in L2 (single owner).
__global__ __launch_bounds__(256) void binsort_kernel(
    const unsigned long long* __restrict__ creg,
    const int* __restrict__ rowstart, int* __restrict__ csr) {
    __shared__ int lcur[256];
    int t = threadIdx.x;
    int node0 = blockIdx.x * 256;
    int nodes = NN - node0; if (nodes > 256) nodes = 256;
    if (t < nodes) lcur[t] = rowstart[node0 + t];
    __syncthreads();
    int beg = rowstart[node0];
    int end = rowstart[node0 + nodes];
    for (int i = beg + t; i < end; i += 256) {
        unsigned long long rec = creg[i];
        int s = (int)(rec & 0xffffffffu);
        int d = (int)(rec >> 32);
        int pos = atomicAdd(&lcur[d - node0], 1);
        csr[pos] = s;
    }
}

__global__ __launch_bounds__(256) void convx_kernel(const float* __restrict__ x,
                                                    bf16* __restrict__ xb) {
    int i = blockIdx.x * 256 + threadIdx.x;
    if (i >= NN * 128 / 4) return;
    float4 v = ((const float4*)x)[i];
    bf16x4 o;
    o[0] = (bf16)v.x; o[1] = (bf16)v.y; o[2] = (bf16)v.z; o[3] = (bf16)v.w;
    *(bf16x4*)(xb + (size_t)i * 4) = o;
}

// Wt1[n][k] = k<128 ? W1s[k][n] : W1n[k-128][n]   (256x256, n-major)
// Wt2[n][k] = n<128 ? W2n[k][n] : W2s[k][n-128]
__global__ __launch_bounds__(256) void convw_kernel(
    const float* __restrict__ W1s, const float* __restrict__ W1n,
    const float* __restrict__ W2n, const float* __restrict__ W2s,
    bf16* __restrict__ Wt1, bf16* __restrict__ Wt2) {
    int i = blockIdx.x * 256 + threadIdx.x;
    if (i >= 65536) return;
    int n = i >> 8, k = i & 255;
    float w1 = (k < 128) ? W1s[k * 256 + n] : W1n[(k - 128) * 256 + n];
    Wt1[i] = (bf16)w1;
    float w2 = (n < 128) ? W2n[k * 128 + n] : W2s[k * 128 + (n - 128)];
    Wt2[i] = (bf16)w2;
}

// one wave per node: mean of bf16 feat rows over CSR bucket -> bf16 agg
__global__ __launch_bounds__(256) void gather1_kernel(const bf16* __restrict__ feat,
                                                      const int* __restrict__ rowstart,
                                                      const int* __restrict__ csr,
                                                      bf16* __restrict__ agg) {
    int node = (blockIdx.x * 256 + threadIdx.x) >> 6;
    if (node >= NN) return;
    int lane = threadIdx.x & 63;
    int c = lane * 2;
    int beg = rowstart[node], end = rowstart[node + 1];
    float ax = 0.f, ay = 0.f;
    int i = beg;
    for (; i + 7 < end; i += 8) {
        float lx = 0.f, ly = 0.f;
#pragma unroll
        for (int u = 0; u < 8; ++u) {
            int s = csr[i + u];
            bf16x2 v = *(const bf16x2*)(feat + (size_t)s * 128 + c);
            lx += (float)v[0];
            ly += (float)v[1];
        }
        ax += lx; ay += ly;
    }
    for (; i < end; ++i) {
        int s = csr[i];
        bf16x2 v = *(const bf16x2*)(feat + (size_t)s * 128 + c);
        ax += (float)v[0];
        ay += (float)v[1];
    }
    int deg = end - beg;
    float inv = 1.0f / (float)(deg > 0 ? deg : 1);
    bf16x2 o;
    o[0] = (bf16)(ax * inv);
    o[1] = (bf16)(ay * inv);
    *(bf16x2*)(agg + (size_t)node * 128 + c) = o;
}

// h1 = relu([xb | agg1b] @ Wt1^T + b1) -> bf16. B in registers, A streamed.
__global__ __launch_bounds__(256) void gemm1_kernel(
    const bf16* __restrict__ xb, const bf16* __restrict__ aggb,
    const bf16* __restrict__ Wt, const float* __restrict__ b1,
    bf16* __restrict__ h1b) {
    int w = threadIdx.x >> 6;
    int lane = threadIdx.x & 63;
    int r = lane & 15, quad = lane >> 4;
    int colbase = w * 64;

    bf16x8 bf[4][8];
#pragma unroll
    for (int t = 0; t < 4; ++t)
#pragma unroll
        for (int kk = 0; kk < 8; ++kk)
            bf[t][kk] = *(const bf16x8*)(Wt + (size_t)(colbase + t * 16 + r) * 256
                                         + kk * 32 + quad * 8);
    float bb[4];
#pragma unroll
    for (int t = 0; t < 4; ++t) bb[t] = b1[colbase + t * 16 + r];

    for (int tile = blockIdx.x; tile < MTILES; tile += GEMM_GRID) {
        int m0 = tile * 16;
        int row = m0 + r;
        bf16x8 a[8];
#pragma unroll
        for (int kk = 0; kk < 4; ++kk)
            a[kk] = *(const bf16x8*)(xb + (size_t)row * 128 + kk * 32 + quad * 8);
#pragma unroll
        for (int kk = 4; kk < 8; ++kk)
            a[kk] = *(const bf16x8*)(aggb + (size_t)row * 128 + (kk - 4) * 32 + quad * 8);
        floatx4 acc[4];
#pragma unroll
        for (int t = 0; t < 4; ++t) acc[t] = (floatx4){0.f, 0.f, 0.f, 0.f};
#pragma unroll
        for (int kk = 0; kk < 8; ++kk)
#pragma unroll
            for (int t = 0; t < 4; ++t)
                acc[t] = __builtin_amdgcn_mfma_f32_16x16x32_bf16(a[kk], bf[t][kk],
                                                                 acc[t], 0, 0, 0);
        int mb = m0 + quad * 4;
#pragma unroll
        for (int t = 0; t < 4; ++t) {
            int col = colbase + t * 16 + r;
#pragma unroll
            for (int rr = 0; rr < 4; ++rr) {
                float v = acc[t][rr] + bb[t];
                v = v > 0.f ? v : 0.f;
                h1b[(size_t)(mb + rr) * 256 + col] = (bf16)v;
            }
        }
    }
}

// [z2 | h2self] = h1b @ Wt2^T. Waves 0-1 -> z2 (bf16), waves 2-3 -> h2self+b2 (fp32).
__global__ __launch_bounds__(256) void gemm2_kernel(
    const bf16* __restrict__ h1b, const bf16* __restrict__ Wt,
    const float* __restrict__ b2, bf16* __restrict__ z2b,
    float* __restrict__ h2s) {
    int w = threadIdx.x >> 6;
    int lane = threadIdx.x & 63;
    int r = lane & 15, quad = lane >> 4;
    int colbase = w * 64;

    bf16x8 bf[4][8];
#pragma unroll
    for (int t = 0; t < 4; ++t)
#pragma unroll
        for (int kk = 0; kk < 8; ++kk)
            bf[t][kk] = *(const bf16x8*)(Wt + (size_t)(colbase + t * 16 + r) * 256
                                         + kk * 32 + quad * 8);
    float bb[4];
#pragma unroll
    for (int t = 0; t < 4; ++t)
        bb[t] = (w >= 2) ? b2[colbase - 128 + t * 16 + r] : 0.f;

    for (int tile = blockIdx.x; tile < MTILES; tile += GEMM_GRID) {
        int m0 = tile * 16;
        int row = m0 + r;
        bf16x8 a[8];
#pragma unroll
        for (int kk = 0; kk < 8; ++kk)
            a[kk] = *(const bf16x8*)(h1b + (size_t)row * 256 + kk * 32 + quad * 8);
        floatx4 acc[4];
#pragma unroll
        for (int t = 0; t < 4; ++t) acc[t] = (floatx4){0.f, 0.f, 0.f, 0.f};
#pragma unroll
        for (int kk = 0; kk < 8; ++kk)
#pragma unroll
            for (int t = 0; t < 4; ++t)
                acc[t] = __builtin_amdgcn_mfma_f32_16x16x32_bf16(a[kk], bf[t][kk],
                                                                 acc[t], 0, 0, 0);
        int mb = m0 + quad * 4;
        if (w < 2) {
#pragma unroll
            for (int t = 0; t < 4; ++t) {
                int col = colbase + t * 16 + r;
#pragma unroll
                for (int rr = 0; rr < 4; ++rr)
                    z2b[(size_t)(mb + rr) * 128 + col] = (bf16)acc[t][rr];
            }
        } else {
#pragma unroll
            for (int t = 0; t < 4; ++t) {
                int col = colbase - 128 + t * 16 + r;
#pragma unroll
                for (int rr = 0; rr < 4; ++rr)
                    h2s[(size_t)(mb + rr) * 128 + col] = acc[t][rr] + bb[t];
            }
        }
    }
}

// gather2 + epilogue: mean(z2[neigh]) + h2self -> h2; p = h2.wp[:128], q = h2.wp[128:]
__global__ __launch_bounds__(256) void gather2_kernel(
    const bf16* __restrict__ z2b, const int* __restrict__ rowstart,
    const int* __restrict__ csr, const float* __restrict__ h2s,
    const float* __restrict__ wp, float* __restrict__ p, float* __restrict__ q) {
    int node = (blockIdx.x * 256 + threadIdx.x) >> 6;
    if (node >= NN) return;
    int lane = threadIdx.x & 63;
    int c = lane * 2;
    int beg = rowstart[node], end = rowstart[node + 1];
    float ax = 0.f, ay = 0.f;
    int i = beg;
    for (; i + 7 < end; i += 8) {
        float lx = 0.f, ly = 0.f;
#pragma unroll
        for (int u = 0; u < 8; ++u) {
            int s = csr[i + u];
            bf16x2 v = *(const bf16x2*)(z2b + (size_t)s * 128 + c);
            lx += (float)v[0];
            ly += (float)v[1];
        }
        ax += lx; ay += ly;
    }
    for (; i < end; ++i) {
        int s = csr[i];
        bf16x2 v = *(const bf16x2*)(z2b + (size_t)s * 128 + c);
        ax += (float)v[0];
        ay += (float)v[1];
    }
    int deg = end - beg;
    float inv = 1.0f / (float)(deg > 0 ? deg : 1);
    float v0 = h2s[(size_t)node * 128 + c] + ax * inv;      // b2 already added
    float v1 = h2s[(size_t)node * 128 + c + 1] + ay * inv;
    float pa = v0 * wp[c] + v1 * wp[c + 1];
    float qa = v0 * wp[128 + c] + v1 * wp[129 + c];
#pragma unroll
    for (int off = 32; off > 0; off >>= 1) {
        pa += __shfl_down(pa, off);
        qa += __shfl_down(qa, off);
    }
    if (lane == 0) {
        p[node] = pa;
        q[node] = qa;
    }
}

__global__ __launch_bounds__(256) void score_kernel(
    const int* __restrict__ psrc, const int* __restrict__ pdst,
    const int* __restrict__ nsrc, const int* __restrict__ ndst,
    const float* __restrict__ p, const float* __restrict__ q,
    const float* __restrict__ bp, float* __restrict__ out) {
    int i = blockIdx.x * blockDim.x + threadIdx.x;
    float b = bp[0];
    if (i < EPOS) {
        out[i] = p[psrc[i]] + q[pdst[i]] + b;
    } else if (i < EPOS + ENEG) {
        int j = i - EPOS;
        out[i] = p[nsrc[j]] + q[ndst[j]] + b;
    }
}

extern "C" void kernel_launch(void* const* d_in, const int* in_sizes, int n_in,
                              void* d_out, int out_size, void* d_ws, size_t ws_size,
                              hipStream_t stream) {
    const float* x    = (const float*)d_in[0];
    const int*   msrc = (const int*)d_in[1];
    const int*   mdst = (const int*)d_in[2];
    const int*   psrc = (const int*)d_in[3];
    const int*   pdst = (const int*)d_in[4];
    const int*   nsrc = (const int*)d_in[5];
    const int*   ndst = (const int*)d_in[6];
    const float* W1s  = (const float*)d_in[7];
    const float* W1n  = (const float*)d_in[8];
    const float* b1   = (const float*)d_in[9];
    const float* W2s  = (const float*)d_in[10];
    const float* W2n  = (const float*)d_in[11];
    const float* b2   = (const float*)d_in[12];
    const float* wp   = (const float*)d_in[13];
    const float* bp   = (const float*)d_in[14];

    char* ws = (char*)d_ws;
    int*   cnt      = (int*)ws + I_CNT;
    int*   rowstart = (int*)ws + I_ROW;
    int*   bsum     = (int*)ws + I_BSUM;
    int*   boff     = (int*)ws + I_BOFF;
    int*   ccur     = (int*)ws + I_CCUR;
    int*   csr_src  = (int*)ws + I_CSR;
    unsigned long long* creg = (unsigned long long*)(ws + B_CREG);
    bf16*  xb    = (bf16*)(ws + B_XB);
    bf16*  agg1b = (bf16*)(ws + B_AGG1);
    bf16*  h1b   = (bf16*)(ws + B_H1);
    bf16*  z2b   = (bf16*)(ws + B_Z2);
    float* h2s   = (float*)(ws + B_H2S);
    bf16*  Wt1   = (bf16*)(ws + B_WT1);
    bf16*  Wt2   = (bf16*)(ws + B_WT2);
    float* p     = (float*)(ws + B_P);
    float* q     = (float*)(ws + B_Q);
    float* out   = (float*)d_out;

    hipMemsetAsync(cnt, 0, 50176 * sizeof(int), stream);

    count_kernel<<<(EM + 255) / 256, 256, 0, stream>>>(mdst, cnt, EM);
    scan1_kernel<<<NB, 256, 0, stream>>>(cnt, bsum);
    scan2_kernel<<<1, 256, 0, stream>>>(bsum, boff);
    scan3_kernel<<<NB, 256, 0, stream>>>(cnt, boff, rowstart, ccur);
    bin_kernel<<<(EM + RPB - 1) / RPB, 256, 0, stream>>>(msrc, mdst, ccur, creg);
    binsort_kernel<<<NB, 256, 0, stream>>>(creg, rowstart, csr_src);

    convx_kernel<<<6250, 256, 0, stream>>>(x, xb);
    convw_kernel<<<256, 256, 0, stream>>>(W1s, W1n, W2n, W2s, Wt1, Wt2);

    gather1_kernel<<<(NN * 64 + 255) / 256, 256, 0, stream>>>(xb, rowstart, csr_src, agg1b);
    gemm1_kernel<<<GEMM_GRID, 256, 0, stream>>>(xb, agg1b, Wt1, b1, h1b);
    gemm2_kernel<<<GEMM_GRID, 256, 0, stream>>>(h1b, Wt2, b2, z2b, h2s);
    gather2_kernel<<<(NN * 64 + 255) / 256, 256, 0, stream>>>(z2b, rowstart, csr_src,
                                                              h2s, wp, p, q);
    score_kernel<<<(EPOS + ENEG + 255) / 256, 256, 0, stream>>>(
        psrc, pdst, nsrc, ndst, p, q, bp, out);
}

// Round 7
// 267.926 us; speedup vs baseline: 11.7918x; 1.1328x over previous
//
#include <hip/hip_runtime.h>

// GraphSAGE 2-layer + edge scorer, MI355X.
// R7: gather2's 90 MB fetch (800k x 256B row gathers) eliminated by algebra:
// p[n] = ps[n] + mean(zp[src]) where zp[s]=z2[s].wp_p is a per-node SCALAR.
// gemm2 now computes {zp,zq,ps,qs} in-register (shfl_xor over r-lanes + tiny
// LDS cross-wave combine) -> 800 KB nodev table; z2b/h2s (38.4 MB) never
// materialized. gather2 gathers 16B scalars from an L2-resident table.
// Kept: CSR via binned two-pass build (R6); GEMM B-in-registers (R5);
// mean(h1[src])@W2n == mean((h1@W2n)[src]); score = p[src]+q[dst]+bp.

#define NN 50000
#define EM 800000
#define EPOS 200000
#define ENEG 200000
#define NB 196            // scan blocks / coarse buckets: 196*256 >= NN
#define RPB 4096          // records per bin_kernel block
#define MTILES 3125       // 50000 / 16 exactly
#define GEMM_GRID 512

typedef __bf16 bf16;
typedef bf16 bf16x2 __attribute__((ext_vector_type(2)));
typedef bf16 bf16x4 __attribute__((ext_vector_type(4)));
typedef bf16 bf16x8 __attribute__((ext_vector_type(8)));
typedef float floatx4 __attribute__((ext_vector_type(4)));

// ---- workspace offsets ----
// int-word offsets:
#define I_CNT  0             // 50176
#define I_ROW  50176         // 50432
#define I_BSUM 100608        // 256
#define I_BOFF 100864        // 256
#define I_CCUR 101120        // 256
#define I_CSR  101376        // 800000 -> ends word 901376
// byte offsets:
#define B_CREG 3605504       // 800000 * 8B records (6.4 MB)
#define B_XB   10005504      // 6.4M bf16 (12.8 MB)
#define B_AGG1 22805504      // 6.4M bf16
#define B_H1   35605504      // 12.8M bf16 (25.6 MB)
#define B_NV   61205504      // 50000 float4 (800 KB)
#define B_WT1  62005504      // 65536 bf16
#define B_WT2  62136576      // 65536 bf16
#define B_P    62267648      // 50176 fp32
#define B_Q    62468352      // 50176 fp32
// end ~62.7 MB

__global__ __launch_bounds__(256) void count_kernel(const int* __restrict__ dst,
                                                    int* __restrict__ cnt, int n) {
    int i = blockIdx.x * blockDim.x + threadIdx.x;
    if (i < n) atomicAdd(&cnt[dst[i]], 1);
}

__global__ __launch_bounds__(256) void scan1_kernel(const int* __restrict__ cnt,
                                                    int* __restrict__ bsum) {
    __shared__ int s[256];
    int t = threadIdx.x;
    int i = blockIdx.x * 256 + t;
    s[t] = (i < NN) ? cnt[i] : 0;
    __syncthreads();
    for (int o = 128; o > 0; o >>= 1) {
        if (t < o) s[t] += s[t + o];
        __syncthreads();
    }
    if (t == 0) bsum[blockIdx.x] = s[0];
}

__global__ __launch_bounds__(256) void scan2_kernel(const int* __restrict__ bsum,
                                                    int* __restrict__ boff) {
    __shared__ int s[256];
    int t = threadIdx.x;
    s[t] = (t < NB) ? bsum[t] : 0;
    __syncthreads();
    for (int o = 1; o < 256; o <<= 1) {
        int u = (t >= o) ? s[t - o] : 0;
        __syncthreads();
        s[t] += u;
        __syncthreads();
    }
    if (t < NB) boff[t] = (t == 0) ? 0 : s[t - 1];
}

// rowstart + per-coarse-bucket claim cursors (ccur[b] = boff[b])
__global__ __launch_bounds__(256) void scan3_kernel(const int* __restrict__ cnt,
                                                    const int* __restrict__ boff,
                                                    int* __restrict__ rowstart,
                                                    int* __restrict__ ccur) {
    __shared__ int s[256];
    int t = threadIdx.x;
    int i = blockIdx.x * 256 + t;
    int v = (i < NN) ? cnt[i] : 0;
    s[t] = v;
    __syncthreads();
    for (int o = 1; o < 256; o <<= 1) {
        int u = (t >= o) ? s[t - o] : 0;
        __syncthreads();
        s[t] += u;
        __syncthreads();
    }
    int excl = boff[blockIdx.x] + s[t] - v;
    if (i < NN) rowstart[i] = excl;
    if (i == NN - 1) rowstart[NN] = EM;
    if (t == 0) ccur[blockIdx.x] = boff[blockIdx.x];
}

// pass A: LDS-sort 4096 edges by coarse bucket (dst>>8), flush bucket-grouped
// 8B (src,dst) records into per-bucket regions of creg.
__global__ __launch_bounds__(256) void bin_kernel(const int* __restrict__ src,
                                                  const int* __restrict__ dst,
                                                  int* __restrict__ ccur,
                                                  unsigned long long* __restrict__ creg) {
    __shared__ int hist[NB];
    __shared__ int cnt2[NB];
    __shared__ int goff[NB];
    __shared__ int base[256];
    __shared__ unsigned long long sorted[RPB];
    int t = threadIdx.x;
    int e0 = blockIdx.x * RPB;
    int nrec = EM - e0; if (nrec > RPB) nrec = RPB;

    for (int i = t; i < NB; i += 256) { hist[i] = 0; cnt2[i] = 0; }
    __syncthreads();

    int myb[RPB / 256];
    unsigned long long myrec[RPB / 256];
#pragma unroll
    for (int j = 0; j < RPB / 256; ++j) {
        int idx = j * 256 + t;
        if (idx < nrec) {
            int s = src[e0 + idx], d = dst[e0 + idx];
            myb[j] = d >> 8;
            myrec[j] = ((unsigned long long)(unsigned)d << 32) | (unsigned)s;
            atomicAdd(&hist[myb[j]], 1);
        } else myb[j] = -1;
    }
    __syncthreads();

    base[t] = (t < NB) ? hist[t] : 0;
    __syncthreads();
    for (int o = 1; o < 256; o <<= 1) {
        int u = (t >= o) ? base[t - o] : 0;
        __syncthreads();
        base[t] += u;
        __syncthreads();
    }

    if (t < NB && hist[t] > 0) goff[t] = atomicAdd(&ccur[t], hist[t]);
#pragma unroll
    for (int j = 0; j < RPB / 256; ++j) {
        if (myb[j] >= 0) {
            int rk = atomicAdd(&cnt2[myb[j]], 1);
            sorted[base[myb[j]] - hist[myb[j]] + rk] = myrec[j];
        }
    }
    __syncthreads();

#pragma unroll
    for (int j = 0; j < RPB / 256; ++j) {
        int idx = j * 256 + t;
        if (idx < nrec) {
            unsigned long long rec = sorted[idx];
            int b = (int)(rec >> 40);
            int exb = base[b] - hist[b];
            creg[(size_t)goff[b] + (idx - exb)] = rec;
        }
    }
}

// pass B: one block per coarse bucket; LDS cursors position edges within the
// bucket's exclusively-owned csr range.
__global__ __launch_bounds__(256) void binsort_kernel(
    const unsigned long long* __restrict__ creg,
    const int* __restrict__ rowstart, int* __restrict__ csr) {
    __shared__ int lcur[256];
    int t = threadIdx.x;
    int node0 = blockIdx.x * 256;
    int nodes = NN - node0; if (nodes > 256) nodes = 256;
    if (t < nodes) lcur[t] = rowstart[node0 + t];
    __syncthreads();
    int beg = rowstart[node0];
    int end = rowstart[node0 + nodes];
    for (int i = beg + t; i < end; i += 256) {
        unsigned long long rec = creg[i];
        int s = (int)(rec & 0xffffffffu);
        int d = (int)(rec >> 32);
        int pos = atomicAdd(&lcur[d - node0], 1);
        csr[pos] = s;
    }
}

__global__ __launch_bounds__(256) void convx_kernel(const float* __restrict__ x,
                                                    bf16* __restrict__ xb) {
    int i = blockIdx.x * 256 + threadIdx.x;
    if (i >= NN * 128 / 4) return;
    float4 v = ((const float4*)x)[i];
    bf16x4 o;
    o[0] = (bf16)v.x; o[1] = (bf16)v.y; o[2] = (bf16)v.z; o[3] = (bf16)v.w;
    *(bf16x4*)(xb + (size_t)i * 4) = o;
}

// Wt1[n][k] = k<128 ? W1s[k][n] : W1n[k-128][n]   (256x256, n-major)
// Wt2[n][k] = n<128 ? W2n[k][n] : W2s[k][n-128]
__global__ __launch_bounds__(256) void convw_kernel(
    const float* __restrict__ W1s, const float* __restrict__ W1n,
    const float* __restrict__ W2n, const float* __restrict__ W2s,
    bf16* __restrict__ Wt1, bf16* __restrict__ Wt2) {
    int i = blockIdx.x * 256 + threadIdx.x;
    if (i >= 65536) return;
    int n = i >> 8, k = i & 255;
    float w1 = (k < 128) ? W1s[k * 256 + n] : W1n[(k - 128) * 256 + n];
    Wt1[i] = (bf16)w1;
    float w2 = (n < 128) ? W2n[k * 128 + n] : W2s[k * 128 + (n - 128)];
    Wt2[i] = (bf16)w2;
}

// one wave per node: mean of bf16 feat rows over CSR bucket -> bf16 agg
__global__ __launch_bounds__(256) void gather1_kernel(const bf16* __restrict__ feat,
                                                      const int* __restrict__ rowstart,
                                                      const int* __restrict__ csr,
                                                      bf16* __restrict__ agg) {
    int node = (blockIdx.x * 256 + threadIdx.x) >> 6;
    if (node >= NN) return;
    int lane = threadIdx.x & 63;
    int c = lane * 2;
    int beg = rowstart[node], end = rowstart[node + 1];
    float ax = 0.f, ay = 0.f;
    int i = beg;
    for (; i + 7 < end; i += 8) {
        float lx = 0.f, ly = 0.f;
#pragma unroll
        for (int u = 0; u < 8; ++u) {
            int s = csr[i + u];
            bf16x2 v = *(const bf16x2*)(feat + (size_t)s * 128 + c);
            lx += (float)v[0];
            ly += (float)v[1];
        }
        ax += lx; ay += ly;
    }
    for (; i < end; ++i) {
        int s = csr[i];
        bf16x2 v = *(const bf16x2*)(feat + (size_t)s * 128 + c);
        ax += (float)v[0];
        ay += (float)v[1];
    }
    int deg = end - beg;
    float inv = 1.0f / (float)(deg > 0 ? deg : 1);
    bf16x2 o;
    o[0] = (bf16)(ax * inv);
    o[1] = (bf16)(ay * inv);
    *(bf16x2*)(agg + (size_t)node * 128 + c) = o;
}

// h1 = relu([xb | agg1b] @ Wt1^T + b1) -> bf16. B in registers, A streamed.
__global__ __launch_bounds__(256) void gemm1_kernel(
    const bf16* __restrict__ xb, const bf16* __restrict__ aggb,
    const bf16* __restrict__ Wt, const float* __restrict__ b1,
    bf16* __restrict__ h1b) {
    int w = threadIdx.x >> 6;
    int lane = threadIdx.x & 63;
    int r = lane & 15, quad = lane >> 4;
    int colbase = w * 64;

    bf16x8 bfr[4][8];
#pragma unroll
    for (int t = 0; t < 4; ++t)
#pragma unroll
        for (int kk = 0; kk < 8; ++kk)
            bfr[t][kk] = *(const bf16x8*)(Wt + (size_t)(colbase + t * 16 + r) * 256
                                          + kk * 32 + quad * 8);
    float bb[4];
#pragma unroll
    for (int t = 0; t < 4; ++t) bb[t] = b1[colbase + t * 16 + r];

    for (int tile = blockIdx.x; tile < MTILES; tile += GEMM_GRID) {
        int m0 = tile * 16;
        int row = m0 + r;
        bf16x8 a[8];
#pragma unroll
        for (int kk = 0; kk < 4; ++kk)
            a[kk] = *(const bf16x8*)(xb + (size_t)row * 128 + kk * 32 + quad * 8);
#pragma unroll
        for (int kk = 4; kk < 8; ++kk)
            a[kk] = *(const bf16x8*)(aggb + (size_t)row * 128 + (kk - 4) * 32 + quad * 8);
        floatx4 acc[4];
#pragma unroll
        for (int t = 0; t < 4; ++t) acc[t] = (floatx4){0.f, 0.f, 0.f, 0.f};
#pragma unroll
        for (int kk = 0; kk < 8; ++kk)
#pragma unroll
            for (int t = 0; t < 4; ++t)
                acc[t] = __builtin_amdgcn_mfma_f32_16x16x32_bf16(a[kk], bfr[t][kk],
                                                                 acc[t], 0, 0, 0);
        int mb = m0 + quad * 4;
#pragma unroll
        for (int t = 0; t < 4; ++t) {
            int col = colbase + t * 16 + r;
#pragma unroll
            for (int rr = 0; rr < 4; ++rr) {
                float v = acc[t][rr] + bb[t];
                v = v > 0.f ? v : 0.f;
                h1b[(size_t)(mb + rr) * 256 + col] = (bf16)v;
            }
        }
    }
}

// Fused gemm2: computes per-node scalars nodev[n] = {zp, zq, ps, qs} where
// zp = (h1@W2n)[n].wp[:128], zq = ..wp[128:], ps = (h1@W2s + b2).wp[:128],
// qs = ..wp[128:]. No z2/h2self materialization.
__global__ __launch_bounds__(256) void gemm2_kernel(
    const bf16* __restrict__ h1b, const bf16* __restrict__ Wt,
    const float* __restrict__ b2, const float* __restrict__ wp,
    float4* __restrict__ nodev) {
    __shared__ float lp[4][16];
    __shared__ float lq[4][16];
    int w = threadIdx.x >> 6;
    int lane = threadIdx.x & 63;
    int r = lane & 15, quad = lane >> 4;
    int colbase = w * 64;

    bf16x8 bfr[4][8];
#pragma unroll
    for (int t = 0; t < 4; ++t)
#pragma unroll
        for (int kk = 0; kk < 8; ++kk)
            bfr[t][kk] = *(const bf16x8*)(Wt + (size_t)(colbase + t * 16 + r) * 256
                                          + kk * 32 + quad * 8);
    float bb[4], wA[4], wB[4];
#pragma unroll
    for (int t = 0; t < 4; ++t) {
        int col = colbase + t * 16 + r;
        if (w < 2) {            // z2 half (W2n cols 0..127)
            bb[t] = 0.f;
            wA[t] = wp[col];
            wB[t] = wp[128 + col];
        } else {                // self half (W2s cols 0..127 at col-128)
            int c2 = col - 128;
            bb[t] = b2[c2];
            wA[t] = wp[c2];
            wB[t] = wp[128 + c2];
        }
    }

    for (int tile = blockIdx.x; tile < MTILES; tile += GEMM_GRID) {
        int m0 = tile * 16;
        int row = m0 + r;
        bf16x8 a[8];
#pragma unroll
        for (int kk = 0; kk < 8; ++kk)
            a[kk] = *(const bf16x8*)(h1b + (size_t)row * 256 + kk * 32 + quad * 8);
        floatx4 acc[4];
#pragma unroll
        for (int t = 0; t < 4; ++t) acc[t] = (floatx4){0.f, 0.f, 0.f, 0.f};
#pragma unroll
        for (int kk = 0; kk < 8; ++kk)
#pragma unroll
            for (int t = 0; t < 4; ++t)
                acc[t] = __builtin_amdgcn_mfma_f32_16x16x32_bf16(a[kk], bfr[t][kk],
                                                                 acc[t], 0, 0, 0);
        // per-lane dot with wp over this wave's 4 col-tiles
        float pacc[4], qacc[4];
#pragma unroll
        for (int rr = 0; rr < 4; ++rr) {
            float pr = 0.f, qr = 0.f;
#pragma unroll
            for (int t = 0; t < 4; ++t) {
                float v = acc[t][rr] + bb[t];
                pr += v * wA[t];
                qr += v * wB[t];
            }
            pacc[rr] = pr;
            qacc[rr] = qr;
        }
        // reduce over the 16 r-lanes (same quad)
#pragma unroll
        for (int m = 1; m <= 8; m <<= 1) {
#pragma unroll
            for (int rr = 0; rr < 4; ++rr) {
                pacc[rr] += __shfl_xor(pacc[rr], m);
                qacc[rr] += __shfl_xor(qacc[rr], m);
            }
        }
        if (r == 0) {
#pragma unroll
            for (int rr = 0; rr < 4; ++rr) {
                lp[w][quad * 4 + rr] = pacc[rr];
                lq[w][quad * 4 + rr] = qacc[rr];
            }
        }
        __syncthreads();
        if (threadIdx.x < 16) {
            int rw = threadIdx.x;
            float4 o;
            o.x = lp[0][rw] + lp[1][rw];   // zp
            o.y = lq[0][rw] + lq[1][rw];   // zq
            o.z = lp[2][rw] + lp[3][rw];   // ps (b2 folded in)
            o.w = lq[2][rw] + lq[3][rw];   // qs
            nodev[m0 + rw] = o;
        }
        __syncthreads();
    }
}

// scalar gather: p[n] = ps[n] + mean(zp[src]); q[n] = qs[n] + mean(zq[src]).
// 16 lanes per node; nodev table is 800 KB (L2-resident).
__global__ __launch_bounds__(256) void gather2_kernel(
    const float4* __restrict__ nodev, const int* __restrict__ rowstart,
    const int* __restrict__ csr, float* __restrict__ p, float* __restrict__ q) {
    int t = threadIdx.x;
    int node = blockIdx.x * 16 + (t >> 4);
    if (node >= NN) return;
    int l = t & 15;
    int beg = rowstart[node], end = rowstart[node + 1];
    float pz = 0.f, qz = 0.f;
    for (int i = beg + l; i < end; i += 16) {
        float4 v = nodev[csr[i]];
        pz += v.x;
        qz += v.y;
    }
#pragma unroll
    for (int m = 8; m >= 1; m >>= 1) {
        pz += __shfl_xor(pz, m);
        qz += __shfl_xor(qz, m);
    }
    if (l == 0) {
        int deg = end - beg;
        float inv = 1.0f / (float)(deg > 0 ? deg : 1);
        float4 me = nodev[node];
        p[node] = me.z + pz * inv;
        q[node] = me.w + qz * inv;
    }
}

__global__ __launch_bounds__(256) void score_kernel(
    const int* __restrict__ psrc, const int* __restrict__ pdst,
    const int* __restrict__ nsrc, const int* __restrict__ ndst,
    const float* __restrict__ p, const float* __restrict__ q,
    const float* __restrict__ bp, float* __restrict__ out) {
    int i = blockIdx.x * blockDim.x + threadIdx.x;
    float b = bp[0];
    if (i < EPOS) {
        out[i] = p[psrc[i]] + q[pdst[i]] + b;
    } else if (i < EPOS + ENEG) {
        int j = i - EPOS;
        out[i] = p[nsrc[j]] + q[ndst[j]] + b;
    }
}

extern "C" void kernel_launch(void* const* d_in, const int* in_sizes, int n_in,
                              void* d_out, int out_size, void* d_ws, size_t ws_size,
                              hipStream_t stream) {
    const float* x    = (const float*)d_in[0];
    const int*   msrc = (const int*)d_in[1];
    const int*   mdst = (const int*)d_in[2];
    const int*   psrc = (const int*)d_in[3];
    const int*   pdst = (const int*)d_in[4];
    const int*   nsrc = (const int*)d_in[5];
    const int*   ndst = (const int*)d_in[6];
    const float* W1s  = (const float*)d_in[7];
    const float* W1n  = (const float*)d_in[8];
    const float* b1   = (const float*)d_in[9];
    const float* W2s  = (const float*)d_in[10];
    const float* W2n  = (const float*)d_in[11];
    const float* b2   = (const float*)d_in[12];
    const float* wp   = (const float*)d_in[13];
    const float* bp   = (const float*)d_in[14];

    char* ws = (char*)d_ws;
    int*   cnt      = (int*)ws + I_CNT;
    int*   rowstart = (int*)ws + I_ROW;
    int*   bsum     = (int*)ws + I_BSUM;
    int*   boff     = (int*)ws + I_BOFF;
    int*   ccur     = (int*)ws + I_CCUR;
    int*   csr_src  = (int*)ws + I_CSR;
    unsigned long long* creg = (unsigned long long*)(ws + B_CREG);
    bf16*   xb    = (bf16*)(ws + B_XB);
    bf16*   agg1b = (bf16*)(ws + B_AGG1);
    bf16*   h1b   = (bf16*)(ws + B_H1);
    float4* nodev = (float4*)(ws + B_NV);
    bf16*   Wt1   = (bf16*)(ws + B_WT1);
    bf16*   Wt2   = (bf16*)(ws + B_WT2);
    float*  p     = (float*)(ws + B_P);
    float*  q     = (float*)(ws + B_Q);
    float*  out   = (float*)d_out;

    hipMemsetAsync(cnt, 0, 50176 * sizeof(int), stream);

    count_kernel<<<(EM + 255) / 256, 256, 0, stream>>>(mdst, cnt, EM);
    scan1_kernel<<<NB, 256, 0, stream>>>(cnt, bsum);
    scan2_kernel<<<1, 256, 0, stream>>>(bsum, boff);
    scan3_kernel<<<NB, 256, 0, stream>>>(cnt, boff, rowstart, ccur);
    bin_kernel<<<(EM + RPB - 1) / RPB, 256, 0, stream>>>(msrc, mdst, ccur, creg);
    binsort_kernel<<<NB, 256, 0, stream>>>(creg, rowstart, csr_src);

    convx_kernel<<<6250, 256, 0, stream>>>(x, xb);
    convw_kernel<<<256, 256, 0, stream>>>(W1s, W1n, W2n, W2s, Wt1, Wt2);

    gather1_kernel<<<(NN * 64 + 255) / 256, 256, 0, stream>>>(xb, rowstart, csr_src, agg1b);
    gemm1_kernel<<<GEMM_GRID, 256, 0, stream>>>(xb, agg1b, Wt1, b1, h1b);
    gemm2_kernel<<<GEMM_GRID, 256, 0, stream>>>(h1b, Wt2, b2, wp, nodev);
    gather2_kernel<<<(NN + 15) / 16, 256, 0, stream>>>(nodev, rowstart, csr_src, p, q);
    score_kernel<<<(EPOS + ENEG + 255) / 256, 256, 0, stream>>>(
        psrc, pdst, nsrc, ndst, p, q, bp, out);
}